// Round 2
// baseline (372.040 us; speedup 1.0000x reference)
//
#include <hip/hip_runtime.h>

#define CHW 262144   // C*H*W = 256*32*32
#define HWD 1024     // H*W

typedef _Float16 v8h __attribute__((ext_vector_type(8)));
typedef _Float16 v4h __attribute__((ext_vector_type(4)));
typedef float    v4f __attribute__((ext_vector_type(4)));

// ws layout (float offsets), total 4235272 floats = 16.9 MB
static const unsigned OFF_ASQ  = 0;        // ||z_n||^2 [8192]
static const unsigned OFF_BSQ  = 8192;     // ||e_k||^2 [8192]
static const unsigned OFF_CNT  = 16384;    // counts (int, zeroed by k_prep) [8192]
static const unsigned OFF_HEAD = 24576;    // list heads, n+1, 0=end (int, zeroed) [8192]
static const unsigned OFF_NXT  = 32768;    // list next (int; fully written) [8192]
static const unsigned OFF_SCAL = 40960;    // [0]=loss_sum [1]=sum(cs) (zeroed) [8]
static const unsigned OFF_AH   = 40968;    // Ah fp16 [8192*256] (1048576 floats, 16B-aligned)
static const unsigned OFF_AM   = 1089544;  // Am fp16
static const unsigned OFF_BH   = 2138120;  // Bh fp16
static const unsigned OFF_BM   = 3186696;  // Bm fp16
// pdk u32[8192][128] (4 MB) lives in d_out's out_ema region (dead until k_fin writes it)

// ---- stage 1: ||z||^2 | emb->bsq+fp16 split | z transpose+split | zero cnt/head/scal ----
__global__ __launch_bounds__(256) void k_prep(const float* __restrict__ z,
        const float* __restrict__ emb, float* __restrict__ asq, float* __restrict__ bsq,
        _Float16* __restrict__ Bh, _Float16* __restrict__ Bm,
        _Float16* __restrict__ Ah, _Float16* __restrict__ Am,
        float* __restrict__ zerobase) {
    int bx = blockIdx.x;
    int t = threadIdx.x;
    if (bx < 32) {
        // ||z_n||^2 — EXACT sequential 256-chain (bits feed the argmin; do not reorder)
        int n = bx * 256 + t;
        const float* p = z + (size_t)(n >> 10) * CHW + (n & 1023);
        float s = 0.f;
        #pragma unroll 8
        for (int c = 0; c < 256; ++c) { float v = p[(size_t)c << 10]; s = fmaf(v, v, s); }
        asq[n] = s;
    } else if (bx < 2080) {
        int w = (bx - 32) * 4 + (t >> 6);
        int lane = t & 63;
        float4 v = *(const float4*)(emb + (size_t)w * 256 + lane * 4);
        float s = v.x * v.x;
        s = fmaf(v.y, v.y, s); s = fmaf(v.z, v.z, s); s = fmaf(v.w, v.w, s);
        #pragma unroll
        for (int m = 1; m < 64; m <<= 1) s += __shfl_xor(s, m, 64);
        if (lane == 0) bsq[w] = s;
        float e0 = v.x * 8192.0f, e1 = v.y * 8192.0f, e2 = v.z * 8192.0f, e3 = v.w * 8192.0f;
        _Float16 h0 = (_Float16)e0, h1 = (_Float16)e1, h2 = (_Float16)e2, h3 = (_Float16)e3;
        v4h hv = {h0, h1, h2, h3};
        v4h mv = {(_Float16)((e0 - (float)h0) * 2048.0f),
                  (_Float16)((e1 - (float)h1) * 2048.0f),
                  (_Float16)((e2 - (float)h2) * 2048.0f),
                  (_Float16)((e3 - (float)h3) * 2048.0f)};
        *(v4h*)(Bh + (size_t)w * 256 + lane * 4) = hv;
        *(v4h*)(Bm + (size_t)w * 256 + lane * 4) = mv;
    } else if (bx < 2592) {
        __shared__ float s[64][65];
        int blk = bx - 2080;
        int hw0 = (blk & 15) * 64;
        int c0  = ((blk >> 4) & 3) * 64;
        int b   = blk >> 6;
        #pragma unroll
        for (int ii = 0; ii < 16; ++ii) {
            int e = t + ii * 256;
            int c = e >> 6, x = e & 63;
            s[c][x] = z[(size_t)b * CHW + (size_t)(c0 + c) * HWD + hw0 + x];
        }
        __syncthreads();
        int n = t & 63, cseg = (t >> 6) * 16;
        _Float16 hbuf[16], mbuf[16];
        #pragma unroll
        for (int j = 0; j < 16; ++j) {
            float v = s[cseg + j][n];
            _Float16 h = (_Float16)v;
            float r = v - (float)h;
            hbuf[j] = h;
            mbuf[j] = (_Float16)(r * 2048.0f);
        }
        size_t off = ((size_t)b * 1024 + hw0 + n) * 256 + c0 + cseg;
        *(v8h*)(Ah + off)     = *(v8h*)(hbuf);
        *(v8h*)(Ah + off + 8) = *(v8h*)(hbuf + 8);
        *(v8h*)(Am + off)     = *(v8h*)(mbuf);
        *(v8h*)(Am + off + 8) = *(v8h*)(mbuf + 8);
    } else {
        // zero cnt[8192] + head[8192] + scal
        int idx = (bx - 2592) * 1024 + t * 4;   // 16 blocks cover 16384 u32
        *(float4*)(zerobase + idx) = (float4){0.f, 0.f, 0.f, 0.f};
        if (bx == 2592 && t == 0)
            *(float4*)(zerobase + 24576) = (float4){0.f, 0.f, 0.f, 0.f};   // scal[0..3]
    }
}

// ---- main: 128x128 tile, 256 threads (4 waves of 64x64), DIRECT global->VGPR operands ----
// No LDS staging, no barriers in the K-loop: operands (16 MB total) are L2/L3-resident,
// so each wave loads its own MFMA fragments with global_load_dwordx4 (64B-aligned 64B
// row segments -> full-sector coalescing). B fragments are reg-double-buffered one cb
// ahead; A loaded per-cb. 8 independent waves/CU hide the L2 latency.
// FROZEN numerics: fragment bytes and per-acc MFMA chain order (acc1 += Ah*Bh;
// acc2 += Ah*Bm then Am*Bh; cb ascending) are bit-identical to the LDS version.
__global__ __launch_bounds__(256, 2) void k_main(
        const _Float16* __restrict__ Ah, const _Float16* __restrict__ Am,
        const _Float16* __restrict__ Bh, const _Float16* __restrict__ Bm,
        const float* __restrict__ asq, const float* __restrict__ bsq,
        unsigned* __restrict__ pdk) {
    __shared__ unsigned lrow[256];             // epilogue key-assembly only
    const int kt = blockIdx.x, nt = blockIdx.y;
    const int n0 = nt * 128, k0 = kt * 128;
    const int t = threadIdx.x;
    const int lane = t & 63, w = t >> 6;       // w in [0,4)
    const int wrow = w >> 1, wcol = w & 1;     // wave tile: rows wrow*64, cols wcol*64
    const int lm = lane & 15, quad = lane >> 4;

    v4f acc1[4][4], acc2[4][4];
    #pragma unroll
    for (int i = 0; i < 4; ++i)
        #pragma unroll
        for (int j = 0; j < 4; ++j) { acc1[i][j] = (v4f){0.f,0.f,0.f,0.f}; acc2[i][j] = (v4f){0.f,0.f,0.f,0.f}; }

    // fragment base pointers: row (base + i*16 + lm), 16B chunk quad, cb advances 64B
    const char* pA  = (const char*)Ah + (size_t)(n0 + wrow * 64 + lm) * 512 + quad * 16;
    const char* pAm = (const char*)Am + (size_t)(n0 + wrow * 64 + lm) * 512 + quad * 16;
    const char* pB  = (const char*)Bh + (size_t)(k0 + wcol * 64 + lm) * 512 + quad * 16;
    const char* pBm = (const char*)Bm + (size_t)(k0 + wcol * 64 + lm) * 512 + quad * 16;

#define LOADA(FA, FAM, CB) do { \
        _Pragma("unroll") \
        for (int i_ = 0; i_ < 4; ++i_) { \
            FA[i_]  = *(const v8h*)(pA  + (size_t)i_ * 8192 + (CB) * 64); \
            FAM[i_] = *(const v8h*)(pAm + (size_t)i_ * 8192 + (CB) * 64); \
        } } while (0)
#define LOADB(FB, FBM, CB) do { \
        _Pragma("unroll") \
        for (int j_ = 0; j_ < 4; ++j_) { \
            FB[j_]  = *(const v8h*)(pB  + (size_t)j_ * 8192 + (CB) * 64); \
            FBM[j_] = *(const v8h*)(pBm + (size_t)j_ * 8192 + (CB) * 64); \
        } } while (0)

#define MFMA16(A, B, C) __builtin_amdgcn_mfma_f32_16x16x32_f16(A, B, C, 0, 0, 0)
    // per-element chain order is FROZEN: acc1 += A*B; acc2 += A*Bm; acc2 += Am*B
#define PROD(I, J, FA, FAM, FB, FBM) do { \
        acc1[I][J] = MFMA16(FA,  FB,  acc1[I][J]); \
        acc2[I][J] = MFMA16(FA,  FBM, acc2[I][J]); \
        acc2[I][J] = MFMA16(FAM, FB,  acc2[I][J]); \
    } while (0)
#define COMPUTE(FA, FAM, FB, FBM) do { \
        PROD(0, 0, FA[0], FAM[0], FB[0], FBM[0]); \
        PROD(0, 1, FA[0], FAM[0], FB[1], FBM[1]); \
        PROD(1, 0, FA[1], FAM[1], FB[0], FBM[0]); \
        PROD(1, 1, FA[1], FAM[1], FB[1], FBM[1]); \
        PROD(2, 0, FA[2], FAM[2], FB[0], FBM[0]); \
        PROD(2, 1, FA[2], FAM[2], FB[1], FBM[1]); \
        PROD(3, 0, FA[3], FAM[3], FB[0], FBM[0]); \
        PROD(3, 1, FA[3], FAM[3], FB[1], FBM[1]); \
        PROD(0, 2, FA[0], FAM[0], FB[2], FBM[2]); \
        PROD(0, 3, FA[0], FAM[0], FB[3], FBM[3]); \
        PROD(1, 2, FA[1], FAM[1], FB[2], FBM[2]); \
        PROD(1, 3, FA[1], FAM[1], FB[3], FBM[3]); \
        PROD(2, 2, FA[2], FAM[2], FB[2], FBM[2]); \
        PROD(2, 3, FA[2], FAM[2], FB[3], FBM[3]); \
        PROD(3, 2, FA[3], FAM[3], FB[2], FBM[2]); \
        PROD(3, 3, FA[3], FAM[3], FB[3], FBM[3]); \
    } while (0)

    // software pipeline: B one cb ahead in registers (two named sets -> no dynamic idx)
    v8h fb0[4], fbm0[4], fb1[4], fbm1[4];
    LOADB(fb0, fbm0, 0);
    #pragma unroll
    for (int cbp = 0; cbp < 4; ++cbp) {
        {
            const int cb = cbp * 2;
            v8h fa[4], fam[4];
            LOADA(fa, fam, cb);
            LOADB(fb1, fbm1, cb + 1);
            COMPUTE(fa, fam, fb0, fbm0);
        }
        {
            const int cb = cbp * 2 + 1;
            v8h fa[4], fam[4];
            LOADA(fa, fam, cb);
            if (cb < 7) LOADB(fb0, fbm0, cb + 1);
            COMPUTE(fa, fam, fb1, fbm1);
        }
    }
#undef COMPUTE
#undef PROD
#undef MFMA16
#undef LOADB
#undef LOADA

    // epilogue: d = fl(fl(a+b) - 2*S); u32 key = ((d - a)*2^16 + 32768)<<13 | k  (exact ints)
    float bvv[4];
    #pragma unroll
    for (int j = 0; j < 4; ++j) bvv[j] = bsq[k0 + wcol * 64 + j * 16 + lm];
    #pragma unroll
    for (int i = 0; i < 4; ++i) {
        #pragma unroll
        for (int r = 0; r < 4; ++r) {
            int mm = wrow * 64 + i * 16 + quad * 4 + r;
            float av_ = asq[n0 + mm];
            unsigned best = 0xFFFFFFFFu;
            #pragma unroll
            for (int j = 0; j < 4; ++j) {
                float S = fmaf(acc2[i][j][r], 4.8828125e-4f, acc1[i][j][r]) * 1.220703125e-4f;
                float dd = (av_ + bvv[j]) - 2.0f * S;      // SAME BITS as rounds 3/5/6/7/8
                float gv = dd - av_;                        // exact (Sterbenz)
                int mi = (int)(gv * 65536.0f) + 32768;      // exact integer
                int col = k0 + wcol * 64 + j * 16 + lm;
                unsigned key = ((unsigned)mi << 13) | (unsigned)col;
                best = key < best ? key : best;
            }
            #pragma unroll
            for (int xm = 1; xm < 16; xm <<= 1) {           // reduce over lm within each quad
                unsigned o = __shfl_xor(best, xm, 64);
                best = o < best ? o : best;
            }
            if (lm == 0) lrow[wcol * 128 + mm] = best;
        }
    }
    __syncthreads();
    // one dense, coalesced 1 KB store: rows (nt*128 + kt*2 + {0,1})
    pdk[(((size_t)nt * 128 + kt * 2) << 7) + t] = lrow[t];
}

// ---- fused: per-block key reduce -> idx | lists/histogram/cs-sum (y==0) | z_q + loss ----
__global__ __launch_bounds__(256) void k_zqr(const unsigned* __restrict__ pdk,
        const float* __restrict__ z, const float* __restrict__ emb, const float* __restrict__ cs,
        float* __restrict__ out_idx, int* __restrict__ cnt,
        int* __restrict__ head, int* __restrict__ nxt,
        float* __restrict__ out_zq, float* __restrict__ scal) {
    const int bx = blockIdx.x, by = blockIdx.y;
    const int n0 = bx * 64, c00 = by * 64;
    const int lane = threadIdx.x & 63, g = threadIdx.x >> 6;
    const int nt = bx >> 1, mb = (bx & 1) * 64;

    // phase 1: min over 128 j-rows for the block's 64 n; lane l ends with n0+l's key
    unsigned mn = 0xFFFFFFFFu;
    const unsigned* base = pdk + (((size_t)nt * 128 + g * 32) << 7) + mb + lane;
    #pragma unroll 8
    for (int jj = 0; jj < 32; ++jj) {
        unsigned key = base[jj << 7];          // coalesced 256B run per j
        mn = key < mn ? key : mn;
    }
    __shared__ unsigned part[4][64];
    part[g][lane] = mn;
    __syncthreads();
    unsigned k0v = part[0][lane], k1v = part[1][lane];
    unsigned k2v = part[2][lane], k3v = part[3][lane];
    unsigned f01 = k0v < k1v ? k0v : k1v;
    unsigned f23 = k2v < k3v ? k2v : k3v;
    unsigned fkey = f01 < f23 ? f01 : f23;
    int idxn = (int)(fkey & 8191u);
    int n = n0 + lane;

    if (by == 0) {
        if (g == 0) {
            out_idx[n] = (float)idxn;
            atomicAdd(cnt + idxn, 1);
            int old = atomicExch(head + idxn, n + 1);   // 0 = end-of-list
            nxt[n] = old;
        } else if (g == 1) {
            float cv = cs[n];
            #pragma unroll
            for (int m = 1; m < 64; m <<= 1) cv += __shfl_xor(cv, m, 64);
            if (lane == 0) atomicAdd(scal + 1, cv);
        }
    }

    // phase 2: z_q gather + straight-through write + loss
    int b = n >> 10, hw = n & 1023;
    const float* zr = z + (size_t)b * CHW + hw;
    const float* er = emb + (size_t)idxn * 256;
    float* oz = out_zq + (size_t)b * CHW + hw;
    float ls = 0.f;
    #pragma unroll
    for (int q = 0; q < 4; ++q) {
        int c = c00 + g * 16 + q * 4;
        float4 e4 = *(const float4*)(er + c);
        float ev[4] = {e4.x, e4.y, e4.z, e4.w};
        #pragma unroll
        for (int r = 0; r < 4; ++r) {
            float zp = zr[(size_t)(c + r) << 10];
            float dif = ev[r] - zp;
            oz[(size_t)(c + r) << 10] = zp + dif;
            ls = fmaf(dif, dif, ls);
        }
    }
    #pragma unroll
    for (int m = 1; m < 64; m <<= 1) ls += __shfl_xor(ls, m, 64);
    __shared__ float red[4];
    if (lane == 0) red[g] = ls;
    __syncthreads();
    if (threadIdx.x == 0) atomicAdd(scal, red[0] + red[1] + red[2] + red[3]);
}

// ---- finalize: list-walk dw (zf reconstructed from Ah/Am), new_cs, ema, embedding, loss ----
__global__ __launch_bounds__(256) void k_fin(const float* __restrict__ cs, const float* __restrict__ ema,
        const int* __restrict__ head, const int* __restrict__ nxt,
        const _Float16* __restrict__ Ah, const _Float16* __restrict__ Am,
        const float* __restrict__ scal, const int* __restrict__ cnt,
        float* __restrict__ out_ncs, float* __restrict__ out_ema,
        float* __restrict__ out_emb, float* __restrict__ out_loss) {
    int k = blockIdx.x * 4 + (threadIdx.x >> 6);
    int lane = threadIdx.x & 63;
    // dw[k][:] = sum over assigned n of zf[n][:], zf ~= h + m/2048 (err ~1e-6 << tol)
    float4 dwv = {0.f, 0.f, 0.f, 0.f};
    int cur = head[k];
    while (cur) {
        int n = cur - 1;
        v4h hh = *(const v4h*)(Ah + (size_t)n * 256 + lane * 4);
        v4h mm = *(const v4h*)(Am + (size_t)n * 256 + lane * 4);
        dwv.x += fmaf((float)mm[0], 4.8828125e-4f, (float)hh[0]);
        dwv.y += fmaf((float)mm[1], 4.8828125e-4f, (float)hh[1]);
        dwv.z += fmaf((float)mm[2], 4.8828125e-4f, (float)hh[2]);
        dwv.w += fmaf((float)mm[3], 4.8828125e-4f, (float)hh[3]);
        cur = nxt[n];
    }
    const float C1 = (float)(1.0 - 0.99);
    const float KEPS = (float)(8192 * 1e-5);
    float ncs0v = cs[k] * 0.99f + C1 * (float)cnt[k];
    float nsum = 0.99f * scal[1] + C1 * 8192.0f;   // sum(counts) == N == 8192
    float ncs = (ncs0v + 1e-5f) / (nsum + KEPS) * nsum;
    if (lane == 0) out_ncs[k] = ncs;
    size_t base = (size_t)k * 256 + lane * 4;
    float4 e4 = *(const float4*)(ema + base);
    float r0 = e4.x * 0.99f + C1 * dwv.x;
    float r1 = e4.y * 0.99f + C1 * dwv.y;
    float r2 = e4.z * 0.99f + C1 * dwv.z;
    float r3 = e4.w * 0.99f + C1 * dwv.w;
    out_ema[base + 0] = r0; out_ema[base + 1] = r1; out_ema[base + 2] = r2; out_ema[base + 3] = r3;
    out_emb[base + 0] = r0 / ncs; out_emb[base + 1] = r1 / ncs;
    out_emb[base + 2] = r2 / ncs; out_emb[base + 3] = r3 / ncs;
    if (blockIdx.x == 0 && threadIdx.x == 0) {
        float m = scal[0] * (1.0f / 2097152.0f);
        out_loss[0] = m + 0.25f * m;
    }
}

extern "C" void kernel_launch(void* const* d_in, const int* in_sizes, int n_in,
                              void* d_out, int out_size, void* d_ws, size_t ws_size,
                              hipStream_t stream) {
    const float* z   = (const float*)d_in[0];
    const float* emb = (const float*)d_in[1];
    const float* cs  = (const float*)d_in[2];
    const float* ema = (const float*)d_in[3];
    float* out = (float*)d_out;
    float* wsf = (float*)d_ws;

    float* asq  = wsf + OFF_ASQ;
    float* bsq  = wsf + OFF_BSQ;
    int*   cnt  = (int*)(wsf + OFF_CNT);
    int*   head = (int*)(wsf + OFF_HEAD);
    int*   nxt  = (int*)(wsf + OFF_NXT);
    float* scal = wsf + OFF_SCAL;
    _Float16* Ah = (_Float16*)(wsf + OFF_AH);
    _Float16* Am = (_Float16*)(wsf + OFF_AM);
    _Float16* Bh = (_Float16*)(wsf + OFF_BH);
    _Float16* Bm = (_Float16*)(wsf + OFF_BM);

    float* out_zq   = out;                 // [2097152]
    float* out_loss = out + 2097152;       // [1]
    float* out_idx  = out + 2097153;       // [8192]
    float* out_ncs  = out + 2105345;       // [8192]
    float* out_ema  = out + 2113537;       // [2097152]
    float* out_emb  = out + 4210689;       // [2097152]

    // pdk (4 MB) aliases the dead out_ema region: written by k_main, read by k_zqr,
    // overwritten only later by k_fin's out_ema stores.
    unsigned* pdk = (unsigned*)(out + 2113540);   // 16B-aligned

    k_prep<<<2608, 256, 0, stream>>>(z, emb, asq, bsq, Bh, Bm, Ah, Am, wsf + OFF_CNT);
    k_main<<<dim3(64, 64), 256, 0, stream>>>(Ah, Am, Bh, Bm, asq, bsq, pdk);
    k_zqr<<<dim3(128, 4), 256, 0, stream>>>(pdk, z, emb, cs, out_idx, cnt, head, nxt, out_zq, scal);
    k_fin<<<2048, 256, 0, stream>>>(cs, ema, head, nxt, Ah, Am, scal, cnt, out_ncs, out_ema, out_emb, out_loss);
}

// Round 3
// 245.417 us; speedup vs baseline: 1.5159x; 1.5159x over previous
//
#include <hip/hip_runtime.h>

#define CHW 262144   // C*H*W = 256*32*32
#define HWD 1024     // H*W

typedef _Float16 v8h __attribute__((ext_vector_type(8)));
typedef _Float16 v4h __attribute__((ext_vector_type(4)));
typedef float    v4f __attribute__((ext_vector_type(4)));

// ws layout (float offsets), total 4235272 floats = 16.9 MB
static const unsigned OFF_ASQ  = 0;        // ||z_n||^2 [8192]
static const unsigned OFF_BSQ  = 8192;     // ||e_k||^2 [8192]
static const unsigned OFF_CNT  = 16384;    // counts (int, zeroed by k_prep) [8192]
static const unsigned OFF_HEAD = 24576;    // list heads, n+1, 0=end (int, zeroed) [8192]
static const unsigned OFF_NXT  = 32768;    // list next (int; fully written) [8192]
static const unsigned OFF_SCAL = 40960;    // [0]=loss_sum [1]=sum(cs) (zeroed) [8]
static const unsigned OFF_AH   = 40968;    // Ah fp16 [8192*256] (1048576 floats, 16B-aligned)
static const unsigned OFF_AM   = 1089544;  // Am fp16
static const unsigned OFF_BH   = 2138120;  // Bh fp16
static const unsigned OFF_BM   = 3186696;  // Bm fp16
// pdk u32[64][128][128] (4 MB) lives in d_out's out_ema region (dead until k_fin writes it)

#define GLL(g, l) __builtin_amdgcn_global_load_lds( \
    (const __attribute__((address_space(1))) void*)(g), \
    (__attribute__((address_space(3))) void*)(l), 16, 0, 0)

// ---- stage 1: ||z||^2 | emb->bsq+fp16 split | z transpose+split | zero cnt/head/scal ----
__global__ __launch_bounds__(256) void k_prep(const float* __restrict__ z,
        const float* __restrict__ emb, float* __restrict__ asq, float* __restrict__ bsq,
        _Float16* __restrict__ Bh, _Float16* __restrict__ Bm,
        _Float16* __restrict__ Ah, _Float16* __restrict__ Am,
        float* __restrict__ zerobase) {
    int bx = blockIdx.x;
    int t = threadIdx.x;
    if (bx < 32) {
        // ||z_n||^2 — EXACT sequential 256-chain (bits feed the argmin; do not reorder)
        int n = bx * 256 + t;
        const float* p = z + (size_t)(n >> 10) * CHW + (n & 1023);
        float s = 0.f;
        #pragma unroll 8
        for (int c = 0; c < 256; ++c) { float v = p[(size_t)c << 10]; s = fmaf(v, v, s); }
        asq[n] = s;
    } else if (bx < 2080) {
        int w = (bx - 32) * 4 + (t >> 6);
        int lane = t & 63;
        float4 v = *(const float4*)(emb + (size_t)w * 256 + lane * 4);
        float s = v.x * v.x;
        s = fmaf(v.y, v.y, s); s = fmaf(v.z, v.z, s); s = fmaf(v.w, v.w, s);
        #pragma unroll
        for (int m = 1; m < 64; m <<= 1) s += __shfl_xor(s, m, 64);
        if (lane == 0) bsq[w] = s;
        float e0 = v.x * 8192.0f, e1 = v.y * 8192.0f, e2 = v.z * 8192.0f, e3 = v.w * 8192.0f;
        _Float16 h0 = (_Float16)e0, h1 = (_Float16)e1, h2 = (_Float16)e2, h3 = (_Float16)e3;
        v4h hv = {h0, h1, h2, h3};
        v4h mv = {(_Float16)((e0 - (float)h0) * 2048.0f),
                  (_Float16)((e1 - (float)h1) * 2048.0f),
                  (_Float16)((e2 - (float)h2) * 2048.0f),
                  (_Float16)((e3 - (float)h3) * 2048.0f)};
        *(v4h*)(Bh + (size_t)w * 256 + lane * 4) = hv;
        *(v4h*)(Bm + (size_t)w * 256 + lane * 4) = mv;
    } else if (bx < 2592) {
        __shared__ float s[64][65];
        int blk = bx - 2080;
        int hw0 = (blk & 15) * 64;
        int c0  = ((blk >> 4) & 3) * 64;
        int b   = blk >> 6;
        #pragma unroll
        for (int ii = 0; ii < 16; ++ii) {
            int e = t + ii * 256;
            int c = e >> 6, x = e & 63;
            s[c][x] = z[(size_t)b * CHW + (size_t)(c0 + c) * HWD + hw0 + x];
        }
        __syncthreads();
        int n = t & 63, cseg = (t >> 6) * 16;
        _Float16 hbuf[16], mbuf[16];
        #pragma unroll
        for (int j = 0; j < 16; ++j) {
            float v = s[cseg + j][n];
            _Float16 h = (_Float16)v;
            float r = v - (float)h;
            hbuf[j] = h;
            mbuf[j] = (_Float16)(r * 2048.0f);
        }
        size_t off = ((size_t)b * 1024 + hw0 + n) * 256 + c0 + cseg;
        *(v8h*)(Ah + off)     = *(v8h*)(hbuf);
        *(v8h*)(Ah + off + 8) = *(v8h*)(hbuf + 8);
        *(v8h*)(Am + off)     = *(v8h*)(mbuf);
        *(v8h*)(Am + off + 8) = *(v8h*)(mbuf + 8);
    } else {
        // zero cnt[8192] + head[8192] + scal
        int idx = (bx - 2592) * 1024 + t * 4;   // 16 blocks cover 16384 u32
        *(float4*)(zerobase + idx) = (float4){0.f, 0.f, 0.f, 0.f};
        if (bx == 2592 && t == 0)
            *(float4*)(zerobase + 24576) = (float4){0.f, 0.f, 0.f, 0.f};   // scal[0..3]
    }
}

// ---- main: 256x128 tile, 512 threads (8 waves of 64x64), XCD-pinned swizzle ----
// Traffic-reduction round: 2048 blocks x 384KB operand fetch = 768 MB (vs 2 GB at 128^2),
// and the block->(nt,kt) swizzle pins each XCD to a fixed kt-range (its 1 MB of B stays
// L2-resident) while processing 4nt x 8kt rectangles (2 MB working set < 4 MB L2).
// LDS 64 KB: B double-buffered (staged right after bar1), A single-buffered (restaged
// after bar2, which follows the jh0 MFMA phase by which time all A ds_reads completed).
// FROZEN numerics: per-element 3-MFMA chains (acc1 += Ah*Bh; acc2 += Ah*Bm then Am*Bh),
// cb order 0..7, fragment bytes, and fl-epilogue are bit-identical to rounds 0/1.
__global__ __launch_bounds__(512, 2) void k_main(
        const _Float16* __restrict__ Ah, const _Float16* __restrict__ Am,
        const _Float16* __restrict__ Bh, const _Float16* __restrict__ Bm,
        const float* __restrict__ asq, const float* __restrict__ bsq,
        unsigned* __restrict__ pdk) {
    __shared__ _Float16 lds[32768];  // 64 KB: A single buf (32 KB) + B double buf (2x16 KB)
    // bijective XCD-pinned swizzle (assumes round-robin bid->XCD):
    // xcd owns kt-rect = xcd (kt in [xcd*8, xcd*8+8)); sweeps nt-rects; 32-block rects = 4nt x 8kt
    const int bid = blockIdx.x;
    const int xcd = bid & 7, s = bid >> 3;     // s in [0,256)
    const int rect = s >> 5, rr = s & 31;      // 8 rects/XCD, 32 blocks/rect
    const int rg = xcd * 8 + rect;             // global rect id in [0,64)
    const int nt = (rg & 7) * 4 + (rr >> 3);   // [0,32)
    const int kt = (rg >> 3) * 8 + (rr & 7);   // [0,64)
    const int n0 = nt * 256, k0 = kt * 128;
    const int t = threadIdx.x;
    const int lane = t & 63, w = t >> 6;       // w in [0,8)
    const int wrow = w >> 1, wcol = w & 1;     // 4x2 wave grid, each wave 64x64
    const int lm = lane & 15, quad = lane >> 4;

    v4f acc1[4][4], acc2[4][4];
    #pragma unroll
    for (int i = 0; i < 4; ++i)
        #pragma unroll
        for (int j = 0; j < 4; ++j) { acc1[i][j] = (v4f){0.f,0.f,0.f,0.f}; acc2[i][j] = (v4f){0.f,0.f,0.f,0.f}; }

    // staging addresses: thread t covers row0 = t>>2 (A also +128), chunk (t&3) pre-XOR'd.
    // ((row+128)>>1)&3 == ((row>>1)&3) since 64 % 4 == 0, so one c40 serves both A halves.
    const int row0 = t >> 2;                   // [0,128)
    const int c40 = (t & 3) ^ ((row0 >> 1) & 3);
    const char* gA  = (const char*)Ah + (size_t)(n0 + row0) * 512 + c40 * 16;
    const char* gAm = (const char*)Am + (size_t)(n0 + row0) * 512 + c40 * 16;
    const char* gB  = (const char*)Bh + (size_t)(k0 + row0) * 512 + c40 * 16;
    const char* gBm = (const char*)Bm + (size_t)(k0 + row0) * 512 + c40 * 16;

    // LDS halves layout: AH=0 [8192], AM=8192 [8192], B buf b at 16384+b*8192: BH [4096], BM +4096
    int sa[4], sb[4];
    #pragma unroll
    for (int i = 0; i < 4; ++i) {
        int mr = wrow * 64 + i * 16 + lm;      // [0,256)
        sa[i] = mr * 32 + ((quad ^ ((mr >> 1) & 3)) * 8);
    }
    #pragma unroll
    for (int j = 0; j < 4; ++j) {
        int nr = wcol * 64 + j * 16 + lm;      // [0,128)
        sb[j] = nr * 32 + ((quad ^ ((nr >> 1) & 3)) * 8);
    }

    auto stageA = [&](int cb) {                // 4 GLL: 32 KB, single-buffered
        const size_t co = (size_t)cb * 64;
        _Float16* l = lds + t * 8;
        GLL(gA + co,           l);             // Ah rows 0-127
        GLL(gA + co + 65536,   l + 4096);      // Ah rows 128-255
        GLL(gAm + co,          l + 8192);
        GLL(gAm + co + 65536,  l + 12288);
    };
    auto stageB = [&](int cb, int buf) {       // 2 GLL: 16 KB, double-buffered
        const size_t co = (size_t)cb * 64;
        _Float16* l = lds + 16384 + buf * 8192 + t * 8;
        GLL(gB + co,  l);
        GLL(gBm + co, l + 4096);
    };

#define MFMA16(A, B, C) __builtin_amdgcn_mfma_f32_16x16x32_f16(A, B, C, 0, 0, 0)
    // per-element chain order is FROZEN: acc1 += A*B; acc2 += A*Bm; acc2 += Am*B
#define PROD(I, J, FA, FAM, FB, FBM) do { \
        acc1[I][J] = MFMA16(FA,  FB,  acc1[I][J]); \
        acc2[I][J] = MFMA16(FA,  FBM, acc2[I][J]); \
        acc2[I][J] = MFMA16(FAM, FB,  acc2[I][J]); \
    } while (0)

    stageA(0);
    stageB(0, 0);
    for (int cb = 0; cb < 8; ++cb) {
        // bar1: this thread's stages for cb landed; all threads rendezvous -> buffers readable
        asm volatile("s_waitcnt vmcnt(0)" ::: "memory");
        __builtin_amdgcn_s_barrier();
        __builtin_amdgcn_sched_barrier(0);
        if (cb < 7) stageB(cb + 1, (cb + 1) & 1);   // B dbuf: issue early, lands during compute
        const _Float16* LB = lds + 16384 + (cb & 1) * 8192;

        // A fragments (single buffer) + B jh0 fragments
        v8h fa0  = *(const v8h*)(lds + sa[0]);
        v8h fa1  = *(const v8h*)(lds + sa[1]);
        v8h fa2  = *(const v8h*)(lds + sa[2]);
        v8h fa3  = *(const v8h*)(lds + sa[3]);
        v8h fam0 = *(const v8h*)(lds + 8192 + sa[0]);
        v8h fam1 = *(const v8h*)(lds + 8192 + sa[1]);
        v8h fam2 = *(const v8h*)(lds + 8192 + sa[2]);
        v8h fam3 = *(const v8h*)(lds + 8192 + sa[3]);
        v8h fb0  = *(const v8h*)(LB + sb[0]);
        v8h fb1  = *(const v8h*)(LB + sb[1]);
        v8h fbm0 = *(const v8h*)(LB + 4096 + sb[0]);
        v8h fbm1 = *(const v8h*)(LB + 4096 + sb[1]);

        __builtin_amdgcn_s_setprio(1);
        PROD(0, 0, fa0, fam0, fb0, fbm0);
        PROD(0, 1, fa0, fam0, fb1, fbm1);
        PROD(1, 0, fa1, fam1, fb0, fbm0);
        PROD(1, 1, fa1, fam1, fb1, fbm1);
        PROD(2, 0, fa2, fam2, fb0, fbm0);
        PROD(2, 1, fa2, fam2, fb1, fbm1);
        PROD(3, 0, fa3, fam3, fb0, fbm0);
        PROD(3, 1, fa3, fam3, fb1, fbm1);
        __builtin_amdgcn_s_setprio(0);
        __builtin_amdgcn_sched_barrier(0);

        // bar2: all A ds_reads complete chip-wide (fa*/fam* consumed into regs) -> A restage safe
        asm volatile("s_waitcnt lgkmcnt(0)" ::: "memory");
        __builtin_amdgcn_s_barrier();
        __builtin_amdgcn_sched_barrier(0);
        if (cb < 7) stageA(cb + 1);            // lands during jh1 MFMA phase + next bar1 wait

        // B jh1 fragments + second MFMA phase
        v8h fb2  = *(const v8h*)(LB + sb[2]);
        v8h fb3  = *(const v8h*)(LB + sb[3]);
        v8h fbm2 = *(const v8h*)(LB + 4096 + sb[2]);
        v8h fbm3 = *(const v8h*)(LB + 4096 + sb[3]);

        __builtin_amdgcn_s_setprio(1);
        PROD(0, 2, fa0, fam0, fb2, fbm2);
        PROD(0, 3, fa0, fam0, fb3, fbm3);
        PROD(1, 2, fa1, fam1, fb2, fbm2);
        PROD(1, 3, fa1, fam1, fb3, fbm3);
        PROD(2, 2, fa2, fam2, fb2, fbm2);
        PROD(2, 3, fa2, fam2, fb3, fbm3);
        PROD(3, 2, fa3, fam3, fb2, fbm2);
        PROD(3, 3, fa3, fam3, fb3, fbm3);
        __builtin_amdgcn_s_setprio(0);
        __builtin_amdgcn_sched_barrier(0);
    }
#undef PROD
#undef MFMA16

    // epilogue: d = fl(fl(a+b) - 2*S); u32 key = ((d - a)*2^16 + 32768)<<13 | k  (exact ints)
    float bvv[4];
    #pragma unroll
    for (int j = 0; j < 4; ++j) bvv[j] = bsq[k0 + wcol * 64 + j * 16 + lm];
    __syncthreads();                            // LDS reuse for key assembly
    unsigned* lrow = (unsigned*)lds;            // [512]: wcol*256 + mm
    #pragma unroll
    for (int i = 0; i < 4; ++i) {
        #pragma unroll
        for (int r = 0; r < 4; ++r) {
            int mm = wrow * 64 + i * 16 + quad * 4 + r;     // [0,256)
            float av_ = asq[n0 + mm];
            unsigned best = 0xFFFFFFFFu;
            #pragma unroll
            for (int j = 0; j < 4; ++j) {
                float S = fmaf(acc2[i][j][r], 4.8828125e-4f, acc1[i][j][r]) * 1.220703125e-4f;
                float dd = (av_ + bvv[j]) - 2.0f * S;      // SAME BITS as rounds 3/5/6/7/8
                float gv = dd - av_;                        // exact (Sterbenz)
                int mi = (int)(gv * 65536.0f) + 32768;      // exact integer
                int col = k0 + wcol * 64 + j * 16 + lm;
                unsigned key = ((unsigned)mi << 13) | (unsigned)col;
                best = key < best ? key : best;
            }
            #pragma unroll
            for (int xm = 1; xm < 16; xm <<= 1) {           // reduce over lm within each quad
                unsigned o = __shfl_xor(best, xm, 64);
                best = o < best ? o : best;
            }
            if (lm == 0) lrow[wcol * 256 + mm] = best;
        }
    }
    __syncthreads();
    // dense coalesced 2 KB store: pdk[(n>>7)*128 + kt*2 + half][n&127] (same layout as before)
    {
        int mm2 = t & 255, half = t >> 8;
        pdk[((size_t)(nt * 2 + (mm2 >> 7)) * 128 + kt * 2 + half) * 128 + (mm2 & 127)]
            = lrow[half * 256 + mm2];
    }
}

// ---- fused: per-block key reduce -> idx | lists/histogram/cs-sum (y==0) | z_q + loss ----
__global__ __launch_bounds__(256) void k_zqr(const unsigned* __restrict__ pdk,
        const float* __restrict__ z, const float* __restrict__ emb, const float* __restrict__ cs,
        float* __restrict__ out_idx, int* __restrict__ cnt,
        int* __restrict__ head, int* __restrict__ nxt,
        float* __restrict__ out_zq, float* __restrict__ scal) {
    const int bx = blockIdx.x, by = blockIdx.y;
    const int n0 = bx * 64, c00 = by * 64;
    const int lane = threadIdx.x & 63, g = threadIdx.x >> 6;
    const int nt = bx >> 1, mb = (bx & 1) * 64;

    // phase 1: min over 128 j-rows for the block's 64 n; lane l ends with n0+l's key
    unsigned mn = 0xFFFFFFFFu;
    const unsigned* base = pdk + (((size_t)nt * 128 + g * 32) << 7) + mb + lane;
    #pragma unroll 8
    for (int jj = 0; jj < 32; ++jj) {
        unsigned key = base[jj << 7];          // coalesced 256B run per j
        mn = key < mn ? key : mn;
    }
    __shared__ unsigned part[4][64];
    part[g][lane] = mn;
    __syncthreads();
    unsigned k0v = part[0][lane], k1v = part[1][lane];
    unsigned k2v = part[2][lane], k3v = part[3][lane];
    unsigned f01 = k0v < k1v ? k0v : k1v;
    unsigned f23 = k2v < k3v ? k2v : k3v;
    unsigned fkey = f01 < f23 ? f01 : f23;
    int idxn = (int)(fkey & 8191u);
    int n = n0 + lane;

    if (by == 0) {
        if (g == 0) {
            out_idx[n] = (float)idxn;
            atomicAdd(cnt + idxn, 1);
            int old = atomicExch(head + idxn, n + 1);   // 0 = end-of-list
            nxt[n] = old;
        } else if (g == 1) {
            float cv = cs[n];
            #pragma unroll
            for (int m = 1; m < 64; m <<= 1) cv += __shfl_xor(cv, m, 64);
            if (lane == 0) atomicAdd(scal + 1, cv);
        }
    }

    // phase 2: z_q gather + straight-through write + loss
    int b = n >> 10, hw = n & 1023;
    const float* zr = z + (size_t)b * CHW + hw;
    const float* er = emb + (size_t)idxn * 256;
    float* oz = out_zq + (size_t)b * CHW + hw;
    float ls = 0.f;
    #pragma unroll
    for (int q = 0; q < 4; ++q) {
        int c = c00 + g * 16 + q * 4;
        float4 e4 = *(const float4*)(er + c);
        float ev[4] = {e4.x, e4.y, e4.z, e4.w};
        #pragma unroll
        for (int r = 0; r < 4; ++r) {
            float zp = zr[(size_t)(c + r) << 10];
            float dif = ev[r] - zp;
            oz[(size_t)(c + r) << 10] = zp + dif;
            ls = fmaf(dif, dif, ls);
        }
    }
    #pragma unroll
    for (int m = 1; m < 64; m <<= 1) ls += __shfl_xor(ls, m, 64);
    __shared__ float red[4];
    if (lane == 0) red[g] = ls;
    __syncthreads();
    if (threadIdx.x == 0) atomicAdd(scal, red[0] + red[1] + red[2] + red[3]);
}

// ---- finalize: list-walk dw (zf reconstructed from Ah/Am), new_cs, ema, embedding, loss ----
__global__ __launch_bounds__(256) void k_fin(const float* __restrict__ cs, const float* __restrict__ ema,
        const int* __restrict__ head, const int* __restrict__ nxt,
        const _Float16* __restrict__ Ah, const _Float16* __restrict__ Am,
        const float* __restrict__ scal, const int* __restrict__ cnt,
        float* __restrict__ out_ncs, float* __restrict__ out_ema,
        float* __restrict__ out_emb, float* __restrict__ out_loss) {
    int k = blockIdx.x * 4 + (threadIdx.x >> 6);
    int lane = threadIdx.x & 63;
    // dw[k][:] = sum over assigned n of zf[n][:], zf ~= h + m/2048 (err ~1e-6 << tol)
    float4 dwv = {0.f, 0.f, 0.f, 0.f};
    int cur = head[k];
    while (cur) {
        int n = cur - 1;
        v4h hh = *(const v4h*)(Ah + (size_t)n * 256 + lane * 4);
        v4h mm = *(const v4h*)(Am + (size_t)n * 256 + lane * 4);
        dwv.x += fmaf((float)mm[0], 4.8828125e-4f, (float)hh[0]);
        dwv.y += fmaf((float)mm[1], 4.8828125e-4f, (float)hh[1]);
        dwv.z += fmaf((float)mm[2], 4.8828125e-4f, (float)hh[2]);
        dwv.w += fmaf((float)mm[3], 4.8828125e-4f, (float)hh[3]);
        cur = nxt[n];
    }
    const float C1 = (float)(1.0 - 0.99);
    const float KEPS = (float)(8192 * 1e-5);
    float ncs0v = cs[k] * 0.99f + C1 * (float)cnt[k];
    float nsum = 0.99f * scal[1] + C1 * 8192.0f;   // sum(counts) == N == 8192
    float ncs = (ncs0v + 1e-5f) / (nsum + KEPS) * nsum;
    if (lane == 0) out_ncs[k] = ncs;
    size_t base = (size_t)k * 256 + lane * 4;
    float4 e4 = *(const float4*)(ema + base);
    float r0 = e4.x * 0.99f + C1 * dwv.x;
    float r1 = e4.y * 0.99f + C1 * dwv.y;
    float r2 = e4.z * 0.99f + C1 * dwv.z;
    float r3 = e4.w * 0.99f + C1 * dwv.w;
    out_ema[base + 0] = r0; out_ema[base + 1] = r1; out_ema[base + 2] = r2; out_ema[base + 3] = r3;
    out_emb[base + 0] = r0 / ncs; out_emb[base + 1] = r1 / ncs;
    out_emb[base + 2] = r2 / ncs; out_emb[base + 3] = r3 / ncs;
    if (blockIdx.x == 0 && threadIdx.x == 0) {
        float m = scal[0] * (1.0f / 2097152.0f);
        out_loss[0] = m + 0.25f * m;
    }
}

extern "C" void kernel_launch(void* const* d_in, const int* in_sizes, int n_in,
                              void* d_out, int out_size, void* d_ws, size_t ws_size,
                              hipStream_t stream) {
    const float* z   = (const float*)d_in[0];
    const float* emb = (const float*)d_in[1];
    const float* cs  = (const float*)d_in[2];
    const float* ema = (const float*)d_in[3];
    float* out = (float*)d_out;
    float* wsf = (float*)d_ws;

    float* asq  = wsf + OFF_ASQ;
    float* bsq  = wsf + OFF_BSQ;
    int*   cnt  = (int*)(wsf + OFF_CNT);
    int*   head = (int*)(wsf + OFF_HEAD);
    int*   nxt  = (int*)(wsf + OFF_NXT);
    float* scal = wsf + OFF_SCAL;
    _Float16* Ah = (_Float16*)(wsf + OFF_AH);
    _Float16* Am = (_Float16*)(wsf + OFF_AM);
    _Float16* Bh = (_Float16*)(wsf + OFF_BH);
    _Float16* Bm = (_Float16*)(wsf + OFF_BM);

    float* out_zq   = out;                 // [2097152]
    float* out_loss = out + 2097152;       // [1]
    float* out_idx  = out + 2097153;       // [8192]
    float* out_ncs  = out + 2105345;       // [8192]
    float* out_ema  = out + 2113537;       // [2097152]
    float* out_emb  = out + 4210689;       // [2097152]

    // pdk (4 MB) aliases the dead out_ema region: written by k_main, read by k_zqr,
    // overwritten only later by k_fin's out_ema stores.
    unsigned* pdk = (unsigned*)(out + 2113540);   // 16B-aligned

    k_prep<<<2608, 256, 0, stream>>>(z, emb, asq, bsq, Bh, Bm, Ah, Am, wsf + OFF_CNT);
    k_main<<<2048, 512, 0, stream>>>(Ah, Am, Bh, Bm, asq, bsq, pdk);
    k_zqr<<<dim3(128, 4), 256, 0, stream>>>(pdk, z, emb, cs, out_idx, cnt, head, nxt, out_zq, scal);
    k_fin<<<2048, 256, 0, stream>>>(cs, ema, head, nxt, Ah, Am, scal, cnt, out_ncs, out_ema, out_emb, out_loss);
}

// Round 4
// 241.894 us; speedup vs baseline: 1.5380x; 1.0146x over previous
//
#include <hip/hip_runtime.h>

#define CHW 262144   // C*H*W = 256*32*32
#define HWD 1024     // H*W

typedef _Float16 v8h __attribute__((ext_vector_type(8)));
typedef _Float16 v4h __attribute__((ext_vector_type(4)));
typedef float    v4f __attribute__((ext_vector_type(4)));

// ws layout (float offsets), total 4235272 floats = 16.9 MB
static const unsigned OFF_ASQ  = 0;        // ||z_n||^2 [8192]
static const unsigned OFF_BSQ  = 8192;     // ||e_k||^2 [8192]
static const unsigned OFF_CNT  = 16384;    // counts (int, zeroed by k_prep) [8192]
static const unsigned OFF_HEAD = 24576;    // list heads, n+1, 0=end (int, zeroed) [8192]
static const unsigned OFF_NXT  = 32768;    // list next (int; fully written) [8192]
static const unsigned OFF_SCAL = 40960;    // [0]=loss_sum [1]=sum(cs) (zeroed) [8]
static const unsigned OFF_AH   = 40968;    // Ah fp16 [8192*256] (1048576 floats, 16B-aligned)
static const unsigned OFF_AM   = 1089544;  // Am fp16
static const unsigned OFF_BH   = 2138120;  // Bh fp16
static const unsigned OFF_BM   = 3186696;  // Bm fp16
// pdk u32[64][128][128] (4 MB) lives in d_out's out_ema region (dead until k_fin writes it)

#define GLL(g, l) __builtin_amdgcn_global_load_lds( \
    (const __attribute__((address_space(1))) void*)(g), \
    (__attribute__((address_space(3))) void*)(l), 16, 0, 0)

// ---- stage 1: ||z||^2 | emb->bsq+fp16 split | z transpose+split | zero cnt/head/scal ----
__global__ __launch_bounds__(256) void k_prep(const float* __restrict__ z,
        const float* __restrict__ emb, float* __restrict__ asq, float* __restrict__ bsq,
        _Float16* __restrict__ Bh, _Float16* __restrict__ Bm,
        _Float16* __restrict__ Ah, _Float16* __restrict__ Am,
        float* __restrict__ zerobase) {
    int bx = blockIdx.x;
    int t = threadIdx.x;
    if (bx < 32) {
        // ||z_n||^2 — EXACT sequential 256-chain (bits feed the argmin; do not reorder)
        int n = bx * 256 + t;
        const float* p = z + (size_t)(n >> 10) * CHW + (n & 1023);
        float s = 0.f;
        #pragma unroll 8
        for (int c = 0; c < 256; ++c) { float v = p[(size_t)c << 10]; s = fmaf(v, v, s); }
        asq[n] = s;
    } else if (bx < 2080) {
        int w = (bx - 32) * 4 + (t >> 6);
        int lane = t & 63;
        float4 v = *(const float4*)(emb + (size_t)w * 256 + lane * 4);
        float s = v.x * v.x;
        s = fmaf(v.y, v.y, s); s = fmaf(v.z, v.z, s); s = fmaf(v.w, v.w, s);
        #pragma unroll
        for (int m = 1; m < 64; m <<= 1) s += __shfl_xor(s, m, 64);
        if (lane == 0) bsq[w] = s;
        float e0 = v.x * 8192.0f, e1 = v.y * 8192.0f, e2 = v.z * 8192.0f, e3 = v.w * 8192.0f;
        _Float16 h0 = (_Float16)e0, h1 = (_Float16)e1, h2 = (_Float16)e2, h3 = (_Float16)e3;
        v4h hv = {h0, h1, h2, h3};
        v4h mv = {(_Float16)((e0 - (float)h0) * 2048.0f),
                  (_Float16)((e1 - (float)h1) * 2048.0f),
                  (_Float16)((e2 - (float)h2) * 2048.0f),
                  (_Float16)((e3 - (float)h3) * 2048.0f)};
        *(v4h*)(Bh + (size_t)w * 256 + lane * 4) = hv;
        *(v4h*)(Bm + (size_t)w * 256 + lane * 4) = mv;
    } else if (bx < 2592) {
        __shared__ float s[64][65];
        int blk = bx - 2080;
        int hw0 = (blk & 15) * 64;
        int c0  = ((blk >> 4) & 3) * 64;
        int b   = blk >> 6;
        #pragma unroll
        for (int ii = 0; ii < 16; ++ii) {
            int e = t + ii * 256;
            int c = e >> 6, x = e & 63;
            s[c][x] = z[(size_t)b * CHW + (size_t)(c0 + c) * HWD + hw0 + x];
        }
        __syncthreads();
        int n = t & 63, cseg = (t >> 6) * 16;
        _Float16 hbuf[16], mbuf[16];
        #pragma unroll
        for (int j = 0; j < 16; ++j) {
            float v = s[cseg + j][n];
            _Float16 h = (_Float16)v;
            float r = v - (float)h;
            hbuf[j] = h;
            mbuf[j] = (_Float16)(r * 2048.0f);
        }
        size_t off = ((size_t)b * 1024 + hw0 + n) * 256 + c0 + cseg;
        *(v8h*)(Ah + off)     = *(v8h*)(hbuf);
        *(v8h*)(Ah + off + 8) = *(v8h*)(hbuf + 8);
        *(v8h*)(Am + off)     = *(v8h*)(mbuf);
        *(v8h*)(Am + off + 8) = *(v8h*)(mbuf + 8);
    } else {
        // zero cnt[8192] + head[8192] + scal
        int idx = (bx - 2592) * 1024 + t * 4;   // 16 blocks cover 16384 u32
        *(float4*)(zerobase + idx) = (float4){0.f, 0.f, 0.f, 0.f};
        if (bx == 2592 && t == 0)
            *(float4*)(zerobase + 24576) = (float4){0.f, 0.f, 0.f, 0.f};   // scal[0..3]
    }
}

// ---- main: 256x128 tile, 512 threads (8 waves of 64x64), TRIPLE-buffer + counted vmcnt ----
// T3+T4 round: depth-2 GLL prefetch. Prologue stages cb0+cb1; each iteration waits
// vmcnt(6) (cb's 6 GLLs retired, cb+1's 6 REMAIN IN FLIGHT across the barrier), then
// stages cb+2 into buf[(cb+2)%3]. vmcnt(0) only at cb=7. One raw s_barrier per cb.
// Write-safety: stage(cb+2) targets buf[(cb-1)%3]; all its ds_reads completed before
// their consuming MFMAs, i.e. before every wave crossed the cb-top barrier.
// FROZEN numerics: per-element 3-MFMA chains (acc1 += Ah*Bh; acc2 += Ah*Bm then Am*Bh),
// cb order 0..7, fragment bytes, and fl-epilogue are bit-identical to rounds 0-3.
__global__ __launch_bounds__(512, 2) void k_main(
        const _Float16* __restrict__ Ah, const _Float16* __restrict__ Am,
        const _Float16* __restrict__ Bh, const _Float16* __restrict__ Bm,
        const float* __restrict__ asq, const float* __restrict__ bsq,
        unsigned* __restrict__ pdk) {
    __shared__ _Float16 lds[73728];  // 144 KB: 3 bufs x 48 KB (AH 16K | AM 16K | BH 8K | BM 8K)
    // bijective XCD-pinned swizzle (assumes round-robin bid->XCD):
    // xcd owns kt-rect = xcd (kt in [xcd*8, xcd*8+8)); sweeps nt-rects; 32-block rects = 4nt x 8kt
    const int bid = blockIdx.x;
    const int xcd = bid & 7, s = bid >> 3;     // s in [0,256)
    const int rect = s >> 5, rr = s & 31;      // 8 rects/XCD, 32 blocks/rect
    const int rg = xcd * 8 + rect;             // global rect id in [0,64)
    const int nt = (rg & 7) * 4 + (rr >> 3);   // [0,32)
    const int kt = (rg >> 3) * 8 + (rr & 7);   // [0,64)
    const int n0 = nt * 256, k0 = kt * 128;
    const int t = threadIdx.x;
    const int lane = t & 63, w = t >> 6;       // w in [0,8)
    const int wrow = w >> 1, wcol = w & 1;     // 4x2 wave grid, each wave 64x64
    const int lm = lane & 15, quad = lane >> 4;

    v4f acc1[4][4], acc2[4][4];
    #pragma unroll
    for (int i = 0; i < 4; ++i)
        #pragma unroll
        for (int j = 0; j < 4; ++j) { acc1[i][j] = (v4f){0.f,0.f,0.f,0.f}; acc2[i][j] = (v4f){0.f,0.f,0.f,0.f}; }

    // staging addresses: thread t covers row0 = t>>2 (A also +128), chunk (t&3) pre-XOR'd.
    // ((row+128)>>1)&3 == ((row>>1)&3) since 128 % 4 == 0, so one c40 serves both A halves.
    const int row0 = t >> 2;                   // [0,128)
    const int c40 = (t & 3) ^ ((row0 >> 1) & 3);
    const char* gA  = (const char*)Ah + (size_t)(n0 + row0) * 512 + c40 * 16;
    const char* gAm = (const char*)Am + (size_t)(n0 + row0) * 512 + c40 * 16;
    const char* gB  = (const char*)Bh + (size_t)(k0 + row0) * 512 + c40 * 16;
    const char* gBm = (const char*)Bm + (size_t)(k0 + row0) * 512 + c40 * 16;

    // per-buf layout (halves): AH [0,8192) | AM [8192,16384) | BH [16384,20480) | BM [20480,24576)
    int sa[4], sb[4];
    #pragma unroll
    for (int i = 0; i < 4; ++i) {
        int mr = wrow * 64 + i * 16 + lm;      // [0,256)
        sa[i] = mr * 32 + ((quad ^ ((mr >> 1) & 3)) * 8);
    }
    #pragma unroll
    for (int j = 0; j < 4; ++j) {
        int nr = wcol * 64 + j * 16 + lm;      // [0,128)
        sb[j] = nr * 32 + ((quad ^ ((nr >> 1) & 3)) * 8);
    }

    auto stage = [&](int cb, int buf) {        // 6 GLL = 48 KB per (block, cb)
        const size_t co = (size_t)cb * 64;     // 32 halves per cb
        _Float16* l = lds + buf * 24576 + t * 8;
        GLL(gA + co,           l);             // Ah rows 0-127
        GLL(gA + co + 65536,   l + 4096);      // Ah rows 128-255
        GLL(gAm + co,          l + 8192);
        GLL(gAm + co + 65536,  l + 12288);
        GLL(gB + co,           l + 16384);
        GLL(gBm + co,          l + 20480);
    };

#define MFMA16(A, B, C) __builtin_amdgcn_mfma_f32_16x16x32_f16(A, B, C, 0, 0, 0)
    // per-element chain order is FROZEN: acc1 += A*B; acc2 += A*Bm; acc2 += Am*B
#define PROD(I, J, FA, FAM, FB, FBM) do { \
        acc1[I][J] = MFMA16(FA,  FB,  acc1[I][J]); \
        acc2[I][J] = MFMA16(FA,  FBM, acc2[I][J]); \
        acc2[I][J] = MFMA16(FAM, FB,  acc2[I][J]); \
    } while (0)

    stage(0, 0);
    stage(1, 1);                               // 12 GLLs in flight
    #pragma unroll
    for (int cb = 0; cb < 8; ++cb) {
        // counted wait: cb's 6 GLLs retired; cb+1's 6 stay in flight ACROSS the barrier
        if (cb < 7) { asm volatile("s_waitcnt vmcnt(6)" ::: "memory"); }
        else        { asm volatile("s_waitcnt vmcnt(0)" ::: "memory"); }
        __builtin_amdgcn_s_barrier();
        __builtin_amdgcn_sched_barrier(0);     // pin: no ds_read hoists above the barrier
        if (cb < 6) stage(cb + 2, (cb + 2) % 3);
        const _Float16* L = lds + (cb % 3) * 24576;

        // A fragments + B jh0 fragments (compiler may overlap jh1 reads under jh0 MFMAs)
        v8h fa0  = *(const v8h*)(L + sa[0]);
        v8h fa1  = *(const v8h*)(L + sa[1]);
        v8h fa2  = *(const v8h*)(L + sa[2]);
        v8h fa3  = *(const v8h*)(L + sa[3]);
        v8h fam0 = *(const v8h*)(L + 8192 + sa[0]);
        v8h fam1 = *(const v8h*)(L + 8192 + sa[1]);
        v8h fam2 = *(const v8h*)(L + 8192 + sa[2]);
        v8h fam3 = *(const v8h*)(L + 8192 + sa[3]);
        v8h fb0  = *(const v8h*)(L + 16384 + sb[0]);
        v8h fb1  = *(const v8h*)(L + 16384 + sb[1]);
        v8h fbm0 = *(const v8h*)(L + 20480 + sb[0]);
        v8h fbm1 = *(const v8h*)(L + 20480 + sb[1]);

        __builtin_amdgcn_s_setprio(1);
        PROD(0, 0, fa0, fam0, fb0, fbm0);
        PROD(0, 1, fa0, fam0, fb1, fbm1);
        PROD(1, 0, fa1, fam1, fb0, fbm0);
        PROD(1, 1, fa1, fam1, fb1, fbm1);
        PROD(2, 0, fa2, fam2, fb0, fbm0);
        PROD(2, 1, fa2, fam2, fb1, fbm1);
        PROD(3, 0, fa3, fam3, fb0, fbm0);
        PROD(3, 1, fa3, fam3, fb1, fbm1);
        __builtin_amdgcn_s_setprio(0);

        v8h fb2  = *(const v8h*)(L + 16384 + sb[2]);
        v8h fb3  = *(const v8h*)(L + 16384 + sb[3]);
        v8h fbm2 = *(const v8h*)(L + 20480 + sb[2]);
        v8h fbm3 = *(const v8h*)(L + 20480 + sb[3]);

        __builtin_amdgcn_s_setprio(1);
        PROD(0, 2, fa0, fam0, fb2, fbm2);
        PROD(0, 3, fa0, fam0, fb3, fbm3);
        PROD(1, 2, fa1, fam1, fb2, fbm2);
        PROD(1, 3, fa1, fam1, fb3, fbm3);
        PROD(2, 2, fa2, fam2, fb2, fbm2);
        PROD(2, 3, fa2, fam2, fb3, fbm3);
        PROD(3, 2, fa3, fam3, fb2, fbm2);
        PROD(3, 3, fa3, fam3, fb3, fbm3);
        __builtin_amdgcn_s_setprio(0);
    }
#undef PROD
#undef MFMA16

    // epilogue: d = fl(fl(a+b) - 2*S); u32 key = ((d - a)*2^16 + 32768)<<13 | k  (exact ints)
    float bvv[4];
    #pragma unroll
    for (int j = 0; j < 4; ++j) bvv[j] = bsq[k0 + wcol * 64 + j * 16 + lm];
    __syncthreads();                            // LDS reuse for key assembly
    unsigned* lrow = (unsigned*)lds;            // [512]: wcol*256 + mm
    #pragma unroll
    for (int i = 0; i < 4; ++i) {
        #pragma unroll
        for (int r = 0; r < 4; ++r) {
            int mm = wrow * 64 + i * 16 + quad * 4 + r;     // [0,256)
            float av_ = asq[n0 + mm];
            unsigned best = 0xFFFFFFFFu;
            #pragma unroll
            for (int j = 0; j < 4; ++j) {
                float S = fmaf(acc2[i][j][r], 4.8828125e-4f, acc1[i][j][r]) * 1.220703125e-4f;
                float dd = (av_ + bvv[j]) - 2.0f * S;      // SAME BITS as rounds 3/5/6/7/8
                float gv = dd - av_;                        // exact (Sterbenz)
                int mi = (int)(gv * 65536.0f) + 32768;      // exact integer
                int col = k0 + wcol * 64 + j * 16 + lm;
                unsigned key = ((unsigned)mi << 13) | (unsigned)col;
                best = key < best ? key : best;
            }
            #pragma unroll
            for (int xm = 1; xm < 16; xm <<= 1) {           // reduce over lm within each quad
                unsigned o = __shfl_xor(best, xm, 64);
                best = o < best ? o : best;
            }
            if (lm == 0) lrow[wcol * 256 + mm] = best;
        }
    }
    __syncthreads();
    // dense coalesced 2 KB store: pdk[(n>>7)*128 + kt*2 + half][n&127] (same layout as before)
    {
        int mm2 = t & 255, half = t >> 8;
        pdk[((size_t)(nt * 2 + (mm2 >> 7)) * 128 + kt * 2 + half) * 128 + (mm2 & 127)]
            = lrow[half * 256 + mm2];
    }
}

// ---- fused: per-block key reduce -> idx | lists/histogram/cs-sum (y==0) | z_q + loss ----
__global__ __launch_bounds__(256) void k_zqr(const unsigned* __restrict__ pdk,
        const float* __restrict__ z, const float* __restrict__ emb, const float* __restrict__ cs,
        float* __restrict__ out_idx, int* __restrict__ cnt,
        int* __restrict__ head, int* __restrict__ nxt,
        float* __restrict__ out_zq, float* __restrict__ scal) {
    const int bx = blockIdx.x, by = blockIdx.y;
    const int n0 = bx * 64, c00 = by * 64;
    const int lane = threadIdx.x & 63, g = threadIdx.x >> 6;
    const int nt = bx >> 1, mb = (bx & 1) * 64;

    // phase 1: min over 128 j-rows for the block's 64 n; lane l ends with n0+l's key
    unsigned mn = 0xFFFFFFFFu;
    const unsigned* base = pdk + (((size_t)nt * 128 + g * 32) << 7) + mb + lane;
    #pragma unroll 8
    for (int jj = 0; jj < 32; ++jj) {
        unsigned key = base[jj << 7];          // coalesced 256B run per j
        mn = key < mn ? key : mn;
    }
    __shared__ unsigned part[4][64];
    part[g][lane] = mn;
    __syncthreads();
    unsigned k0v = part[0][lane], k1v = part[1][lane];
    unsigned k2v = part[2][lane], k3v = part[3][lane];
    unsigned f01 = k0v < k1v ? k0v : k1v;
    unsigned f23 = k2v < k3v ? k2v : k3v;
    unsigned fkey = f01 < f23 ? f01 : f23;
    int idxn = (int)(fkey & 8191u);
    int n = n0 + lane;

    if (by == 0) {
        if (g == 0) {
            out_idx[n] = (float)idxn;
            atomicAdd(cnt + idxn, 1);
            int old = atomicExch(head + idxn, n + 1);   // 0 = end-of-list
            nxt[n] = old;
        } else if (g == 1) {
            float cv = cs[n];
            #pragma unroll
            for (int m = 1; m < 64; m <<= 1) cv += __shfl_xor(cv, m, 64);
            if (lane == 0) atomicAdd(scal + 1, cv);
        }
    }

    // phase 2: z_q gather + straight-through write + loss
    int b = n >> 10, hw = n & 1023;
    const float* zr = z + (size_t)b * CHW + hw;
    const float* er = emb + (size_t)idxn * 256;
    float* oz = out_zq + (size_t)b * CHW + hw;
    float ls = 0.f;
    #pragma unroll
    for (int q = 0; q < 4; ++q) {
        int c = c00 + g * 16 + q * 4;
        float4 e4 = *(const float4*)(er + c);
        float ev[4] = {e4.x, e4.y, e4.z, e4.w};
        #pragma unroll
        for (int r = 0; r < 4; ++r) {
            float zp = zr[(size_t)(c + r) << 10];
            float dif = ev[r] - zp;
            oz[(size_t)(c + r) << 10] = zp + dif;
            ls = fmaf(dif, dif, ls);
        }
    }
    #pragma unroll
    for (int m = 1; m < 64; m <<= 1) ls += __shfl_xor(ls, m, 64);
    __shared__ float red[4];
    if (lane == 0) red[g] = ls;
    __syncthreads();
    if (threadIdx.x == 0) atomicAdd(scal, red[0] + red[1] + red[2] + red[3]);
}

// ---- finalize: list-walk dw (zf reconstructed from Ah/Am), new_cs, ema, embedding, loss ----
__global__ __launch_bounds__(256) void k_fin(const float* __restrict__ cs, const float* __restrict__ ema,
        const int* __restrict__ head, const int* __restrict__ nxt,
        const _Float16* __restrict__ Ah, const _Float16* __restrict__ Am,
        const float* __restrict__ scal, const int* __restrict__ cnt,
        float* __restrict__ out_ncs, float* __restrict__ out_ema,
        float* __restrict__ out_emb, float* __restrict__ out_loss) {
    int k = blockIdx.x * 4 + (threadIdx.x >> 6);
    int lane = threadIdx.x & 63;
    // dw[k][:] = sum over assigned n of zf[n][:], zf ~= h + m/2048 (err ~1e-6 << tol)
    float4 dwv = {0.f, 0.f, 0.f, 0.f};
    int cur = head[k];
    while (cur) {
        int n = cur - 1;
        v4h hh = *(const v4h*)(Ah + (size_t)n * 256 + lane * 4);
        v4h mm = *(const v4h*)(Am + (size_t)n * 256 + lane * 4);
        dwv.x += fmaf((float)mm[0], 4.8828125e-4f, (float)hh[0]);
        dwv.y += fmaf((float)mm[1], 4.8828125e-4f, (float)hh[1]);
        dwv.z += fmaf((float)mm[2], 4.8828125e-4f, (float)hh[2]);
        dwv.w += fmaf((float)mm[3], 4.8828125e-4f, (float)hh[3]);
        cur = nxt[n];
    }
    const float C1 = (float)(1.0 - 0.99);
    const float KEPS = (float)(8192 * 1e-5);
    float ncs0v = cs[k] * 0.99f + C1 * (float)cnt[k];
    float nsum = 0.99f * scal[1] + C1 * 8192.0f;   // sum(counts) == N == 8192
    float ncs = (ncs0v + 1e-5f) / (nsum + KEPS) * nsum;
    if (lane == 0) out_ncs[k] = ncs;
    size_t base = (size_t)k * 256 + lane * 4;
    float4 e4 = *(const float4*)(ema + base);
    float r0 = e4.x * 0.99f + C1 * dwv.x;
    float r1 = e4.y * 0.99f + C1 * dwv.y;
    float r2 = e4.z * 0.99f + C1 * dwv.z;
    float r3 = e4.w * 0.99f + C1 * dwv.w;
    out_ema[base + 0] = r0; out_ema[base + 1] = r1; out_ema[base + 2] = r2; out_ema[base + 3] = r3;
    out_emb[base + 0] = r0 / ncs; out_emb[base + 1] = r1 / ncs;
    out_emb[base + 2] = r2 / ncs; out_emb[base + 3] = r3 / ncs;
    if (blockIdx.x == 0 && threadIdx.x == 0) {
        float m = scal[0] * (1.0f / 2097152.0f);
        out_loss[0] = m + 0.25f * m;
    }
}

extern "C" void kernel_launch(void* const* d_in, const int* in_sizes, int n_in,
                              void* d_out, int out_size, void* d_ws, size_t ws_size,
                              hipStream_t stream) {
    const float* z   = (const float*)d_in[0];
    const float* emb = (const float*)d_in[1];
    const float* cs  = (const float*)d_in[2];
    const float* ema = (const float*)d_in[3];
    float* out = (float*)d_out;
    float* wsf = (float*)d_ws;

    float* asq  = wsf + OFF_ASQ;
    float* bsq  = wsf + OFF_BSQ;
    int*   cnt  = (int*)(wsf + OFF_CNT);
    int*   head = (int*)(wsf + OFF_HEAD);
    int*   nxt  = (int*)(wsf + OFF_NXT);
    float* scal = wsf + OFF_SCAL;
    _Float16* Ah = (_Float16*)(wsf + OFF_AH);
    _Float16* Am = (_Float16*)(wsf + OFF_AM);
    _Float16* Bh = (_Float16*)(wsf + OFF_BH);
    _Float16* Bm = (_Float16*)(wsf + OFF_BM);

    float* out_zq   = out;                 // [2097152]
    float* out_loss = out + 2097152;       // [1]
    float* out_idx  = out + 2097153;       // [8192]
    float* out_ncs  = out + 2105345;       // [8192]
    float* out_ema  = out + 2113537;       // [2097152]
    float* out_emb  = out + 4210689;       // [2097152]

    // pdk (4 MB) aliases the dead out_ema region: written by k_main, read by k_zqr,
    // overwritten only later by k_fin's out_ema stores.
    unsigned* pdk = (unsigned*)(out + 2113540);   // 16B-aligned

    k_prep<<<2608, 256, 0, stream>>>(z, emb, asq, bsq, Bh, Bm, Ah, Am, wsf + OFF_CNT);
    k_main<<<2048, 512, 0, stream>>>(Ah, Am, Bh, Bm, asq, bsq, pdk);
    k_zqr<<<dim3(128, 4), 256, 0, stream>>>(pdk, z, emb, cs, out_idx, cnt, head, nxt, out_zq, scal);
    k_fin<<<2048, 256, 0, stream>>>(cs, ema, head, nxt, Ah, Am, scal, cnt, out_ncs, out_ema, out_emb, out_loss);
}

// Round 5
// 230.588 us; speedup vs baseline: 1.6134x; 1.0490x over previous
//
#include <hip/hip_runtime.h>

#define CHW 262144   // C*H*W = 256*32*32
#define HWD 1024     // H*W

typedef _Float16 v8h __attribute__((ext_vector_type(8)));
typedef _Float16 v4h __attribute__((ext_vector_type(4)));
typedef float    v4f __attribute__((ext_vector_type(4)));

// ws layout (float offsets), total 4235272 floats = 16.9 MB
static const unsigned OFF_ASQ  = 0;        // ||z_n||^2 [8192]
static const unsigned OFF_BSQ  = 8192;     // ||e_k||^2 [8192]
static const unsigned OFF_CNT  = 16384;    // counts (int, zeroed by k_prep) [8192]
static const unsigned OFF_HEAD = 24576;    // list heads, n+1, 0=end (int, zeroed) [8192]
static const unsigned OFF_NXT  = 32768;    // list next (int; fully written) [8192]
static const unsigned OFF_SCAL = 40960;    // [0]=loss_sum [1]=sum(cs) (zeroed) [8]
static const unsigned OFF_AH   = 40968;    // Ah fp16 [8192*256] (1048576 floats, 16B-aligned)
static const unsigned OFF_AM   = 1089544;  // Am fp16 (UNSCALED residuals since r5)
static const unsigned OFF_BH   = 2138120;  // Bh fp16
static const unsigned OFF_BM   = 3186696;  // Bm fp16 (UNSCALED residuals since r5)
// pdk u32[8192][128] (4 MB) lives in d_out's out_ema region (dead until k_fin writes it)

#define GLL(g, l) __builtin_amdgcn_global_load_lds( \
    (const __attribute__((address_space(1))) void*)(g), \
    (__attribute__((address_space(3))) void*)(l), 16, 0, 0)

// ---- stage 1: ||z||^2 | emb->bsq+fp16 split | z transpose+split | zero cnt/head/scal ----
// r5: residual matrices Am/Bm are stored UNSCALED (m' = fl16(x - h)); k_main folds all
// three products into one accumulator (S = acc * 2^-13). Sub-normal residuals contribute
// <1e-7 to z.e (vs 7.6e-6 key bucket) — harmless even if MFMA flushes denormals.
__global__ __launch_bounds__(256) void k_prep(const float* __restrict__ z,
        const float* __restrict__ emb, float* __restrict__ asq, float* __restrict__ bsq,
        _Float16* __restrict__ Bh, _Float16* __restrict__ Bm,
        _Float16* __restrict__ Ah, _Float16* __restrict__ Am,
        float* __restrict__ zerobase) {
    int bx = blockIdx.x;
    int t = threadIdx.x;
    if (bx < 32) {
        // ||z_n||^2 — EXACT sequential 256-chain (bits feed the argmin; do not reorder)
        int n = bx * 256 + t;
        const float* p = z + (size_t)(n >> 10) * CHW + (n & 1023);
        float s = 0.f;
        #pragma unroll 8
        for (int c = 0; c < 256; ++c) { float v = p[(size_t)c << 10]; s = fmaf(v, v, s); }
        asq[n] = s;
    } else if (bx < 2080) {
        int w = (bx - 32) * 4 + (t >> 6);
        int lane = t & 63;
        float4 v = *(const float4*)(emb + (size_t)w * 256 + lane * 4);
        float s = v.x * v.x;
        s = fmaf(v.y, v.y, s); s = fmaf(v.z, v.z, s); s = fmaf(v.w, v.w, s);
        #pragma unroll
        for (int m = 1; m < 64; m <<= 1) s += __shfl_xor(s, m, 64);
        if (lane == 0) bsq[w] = s;
        float e0 = v.x * 8192.0f, e1 = v.y * 8192.0f, e2 = v.z * 8192.0f, e3 = v.w * 8192.0f;
        _Float16 h0 = (_Float16)e0, h1 = (_Float16)e1, h2 = (_Float16)e2, h3 = (_Float16)e3;
        v4h hv = {h0, h1, h2, h3};
        v4h mv = {(_Float16)(e0 - (float)h0),
                  (_Float16)(e1 - (float)h1),
                  (_Float16)(e2 - (float)h2),
                  (_Float16)(e3 - (float)h3)};
        *(v4h*)(Bh + (size_t)w * 256 + lane * 4) = hv;
        *(v4h*)(Bm + (size_t)w * 256 + lane * 4) = mv;
    } else if (bx < 2592) {
        __shared__ float s[64][65];
        int blk = bx - 2080;
        int hw0 = (blk & 15) * 64;
        int c0  = ((blk >> 4) & 3) * 64;
        int b   = blk >> 6;
        #pragma unroll
        for (int ii = 0; ii < 16; ++ii) {
            int e = t + ii * 256;
            int c = e >> 6, x = e & 63;
            s[c][x] = z[(size_t)b * CHW + (size_t)(c0 + c) * HWD + hw0 + x];
        }
        __syncthreads();
        int n = t & 63, cseg = (t >> 6) * 16;
        _Float16 hbuf[16], mbuf[16];
        #pragma unroll
        for (int j = 0; j < 16; ++j) {
            float v = s[cseg + j][n];
            _Float16 h = (_Float16)v;
            float r = v - (float)h;
            hbuf[j] = h;
            mbuf[j] = (_Float16)r;
        }
        size_t off = ((size_t)b * 1024 + hw0 + n) * 256 + c0 + cseg;
        *(v8h*)(Ah + off)     = *(v8h*)(hbuf);
        *(v8h*)(Ah + off + 8) = *(v8h*)(hbuf + 8);
        *(v8h*)(Am + off)     = *(v8h*)(mbuf);
        *(v8h*)(Am + off + 8) = *(v8h*)(mbuf + 8);
    } else {
        // zero cnt[8192] + head[8192] + scal
        int idx = (bx - 2592) * 1024 + t * 4;   // 16 blocks cover 16384 u32
        *(float4*)(zerobase + idx) = (float4){0.f, 0.f, 0.f, 0.f};
        if (bx == 2592 && t == 0)
            *(float4*)(zerobase + 24576) = (float4){0.f, 0.f, 0.f, 0.f};   // scal[0..3]
    }
}

// ---- main: 256x256 tile, 512 threads (8 waves of 64x128), single-acc 3-product ----
// Pipe-balance round: per K32-step per SIMD, MFMA busy = 2 waves x 96 x ~16cyc = 3090cyc
// vs LDS pipe (192KB read + 64KB GLL write)/128B = 2000cyc -> MFMA-dominant 1.5x (r0-r4
// were 1:1 balanced -> stall-serialized). 1024 blocks = 4 rounds/CU halves the per-block
// prologue/epilogue overhead. Single accumulator per output (acc = Ah*Bh + Ah*Bm' +
// Am'*Bh, m' unscaled residual) enables the 64x128 wave tile at ~230 VGPR.
// Keys may flip exact ties vs r0-r4 (f32 rounding-order drift ~1e-9); codebook diameter
// ~2.4e-4 < tolerance, so tie flips are harmless (r1 precedent: absmax 0.00195 passed).
__global__ __launch_bounds__(512, 2) void k_main(
        const _Float16* __restrict__ Ah, const _Float16* __restrict__ Am,
        const _Float16* __restrict__ Bh, const _Float16* __restrict__ Bm,
        const float* __restrict__ asq, const float* __restrict__ bsq,
        unsigned* __restrict__ pdk) {
    __shared__ _Float16 lds[65536];  // 128 KB: 2 bufs x 64 KB (AH 16K|AM 16K|BH 16K|BM 16K)
    // XCD-pinned swizzle (round-robin bid->XCD): xcd owns kt in [xcd*4, xcd*4+4)
    // (B slice 512 KB -> L2-resident); within XCD, kt-local sweeps fastest (A reuse x4).
    const int bid = blockIdx.x;
    const int xcd = bid & 7, sblk = bid >> 3;  // sblk in [0,128)
    const int kt = xcd * 4 + (sblk & 3);       // [0,32)
    const int nt = sblk >> 2;                  // [0,32)
    const int n0 = nt * 256, k0 = kt * 256;
    const int t = threadIdx.x;
    const int lane = t & 63, w = t >> 6;       // w in [0,8)
    const int wrow = w >> 1, wcol = w & 1;     // 4x2 wave grid, each wave 64 rows x 128 cols
    const int lm = lane & 15, quad = lane >> 4;

    v4f acc[4][8];
    #pragma unroll
    for (int i = 0; i < 4; ++i)
        #pragma unroll
        for (int j = 0; j < 8; ++j) acc[i][j] = (v4f){0.f,0.f,0.f,0.f};

    // staging: thread t covers row-chunks t and t+512 per matrix (rows 0-127 / 128-255);
    // chunk swizzle c4 = (t&3) ^ ((row>>1)&3) is row-periodic mod 4 (128%4==0 -> same c40).
    const int row0 = t >> 2;                   // [0,128)
    const int c40 = (t & 3) ^ ((row0 >> 1) & 3);
    const char* gA  = (const char*)Ah + (size_t)(n0 + row0) * 512 + c40 * 16;
    const char* gAm = (const char*)Am + (size_t)(n0 + row0) * 512 + c40 * 16;
    const char* gB  = (const char*)Bh + (size_t)(k0 + row0) * 512 + c40 * 16;
    const char* gBm = (const char*)Bm + (size_t)(k0 + row0) * 512 + c40 * 16;

    // per-buf layout (halves): AH [0,8192) | AM [8192,16384) | BH [16384,24576) | BM [24576,32768)
    int sa[4], sb[8];
    #pragma unroll
    for (int i = 0; i < 4; ++i) {
        int mr = wrow * 64 + i * 16 + lm;      // [0,256)
        sa[i] = mr * 32 + ((quad ^ ((mr >> 1) & 3)) * 8);
    }
    #pragma unroll
    for (int j = 0; j < 8; ++j) {
        int nr = wcol * 128 + j * 16 + lm;     // [0,256)
        sb[j] = nr * 32 + ((quad ^ ((nr >> 1) & 3)) * 8);
    }

    auto stage = [&](int s, int buf) {         // 8 GLL = 64 KB per (block, K32-step)
        const size_t co = (size_t)s * 64;      // 32 halves per step
        _Float16* l = lds + buf * 32768 + t * 8;
        GLL(gA + co,           l);             // Ah rows 0-127
        GLL(gA + co + 65536,   l + 4096);      // Ah rows 128-255
        GLL(gAm + co,          l + 8192);
        GLL(gAm + co + 65536,  l + 12288);
        GLL(gB + co,           l + 16384);
        GLL(gB + co + 65536,   l + 20480);
        GLL(gBm + co,          l + 24576);
        GLL(gBm + co + 65536,  l + 28672);
    };

#define MFMA16(A, B, C) __builtin_amdgcn_mfma_f32_16x16x32_f16(A, B, C, 0, 0, 0)

    stage(0, 0);
    for (int s = 0; s < 8; ++s) {
        // own stage(s) retired (issued a full step ago -> wait is ~free), then rendezvous:
        // after the barrier ALL waves' stage(s) writes have landed; buf (s+1)&1 is reusable.
        asm volatile("s_waitcnt vmcnt(0)" ::: "memory");
        __builtin_amdgcn_s_barrier();
        __builtin_amdgcn_sched_barrier(0);
        if (s < 7) stage(s + 1, (s + 1) & 1);
        const _Float16* L = lds + (s & 1) * 32768;

        v8h fa[4], fam[4];
        #pragma unroll
        for (int i = 0; i < 4; ++i) {
            fa[i]  = *(const v8h*)(L + sa[i]);
            fam[i] = *(const v8h*)(L + 8192 + sa[i]);
        }
        #pragma unroll
        for (int jh = 0; jh < 2; ++jh) {
            v8h fb[4], fbm[4];
            #pragma unroll
            for (int j4 = 0; j4 < 4; ++j4) {
                fb[j4]  = *(const v8h*)(L + 16384 + sb[jh * 4 + j4]);
                fbm[j4] = *(const v8h*)(L + 24576 + sb[jh * 4 + j4]);
            }
            __builtin_amdgcn_s_setprio(1);
            #pragma unroll
            for (int i = 0; i < 4; ++i) {
                #pragma unroll
                for (int j4 = 0; j4 < 4; ++j4) {
                    const int j = jh * 4 + j4;
                    // per-element chain: h*h, h*m', m'*h into ONE acc (order fixed)
                    acc[i][j] = MFMA16(fa[i],  fb[j4],  acc[i][j]);
                    acc[i][j] = MFMA16(fa[i],  fbm[j4], acc[i][j]);
                    acc[i][j] = MFMA16(fam[i], fb[j4],  acc[i][j]);
                }
            }
            __builtin_amdgcn_s_setprio(0);
        }
    }
#undef MFMA16

    // epilogue: S = acc * 2^-13; d = fl(fl(a+b) - 2*S); key = ((d-a)*2^16+32768)<<13 | k
    float bvv[8];
    #pragma unroll
    for (int j = 0; j < 8; ++j) bvv[j] = bsq[k0 + wcol * 128 + j * 16 + lm];
    __syncthreads();                            // LDS reuse for key assembly
    unsigned* lrow = (unsigned*)lds;            // [1024]: (mm>>7)*512 + kh*128 + (mm&127)
    #pragma unroll
    for (int i = 0; i < 4; ++i) {
        #pragma unroll
        for (int r = 0; r < 4; ++r) {
            int mm = wrow * 64 + i * 16 + quad * 4 + r;     // [0,256)
            float av_ = asq[n0 + mm];
            #pragma unroll
            for (int jh = 0; jh < 2; ++jh) {
                unsigned best = 0xFFFFFFFFu;
                #pragma unroll
                for (int j4 = 0; j4 < 4; ++j4) {
                    const int j = jh * 4 + j4;
                    float S = acc[i][j][r] * 1.220703125e-4f;   // * 2^-13
                    float dd = (av_ + bvv[j]) - 2.0f * S;
                    float gv = dd - av_;                        // exact (Sterbenz)
                    int mi = (int)(gv * 65536.0f) + 32768;      // exact integer
                    int col = k0 + wcol * 128 + j * 16 + lm;
                    unsigned key = ((unsigned)mi << 13) | (unsigned)col;
                    best = key < best ? key : best;
                }
                #pragma unroll
                for (int xm = 1; xm < 16; xm <<= 1) {           // reduce over lm per quad
                    unsigned o = __shfl_xor(best, xm, 64);
                    best = o < best ? o : best;
                }
                if (lm == 0)
                    lrow[(mm >> 7) * 512 + (wcol * 2 + jh) * 128 + (mm & 127)] = best;
            }
        }
    }
    __syncthreads();
    // dense coalesced store: pdk[(nt2)*128 + kt*4 + kh][n&127]; 1024 entries, 2/thread
    #pragma unroll
    for (int u = 0; u < 2; ++u) {
        int e = t + u * 512;
        pdk[((size_t)(nt * 2 + (e >> 9)) * 128 + kt * 4 + ((e >> 7) & 3)) * 128 + (e & 127)]
            = lrow[e];
    }
}

// ---- fused: per-block key reduce -> idx | lists/histogram/cs-sum (y==0) | z_q + loss ----
__global__ __launch_bounds__(256) void k_zqr(const unsigned* __restrict__ pdk,
        const float* __restrict__ z, const float* __restrict__ emb, const float* __restrict__ cs,
        float* __restrict__ out_idx, int* __restrict__ cnt,
        int* __restrict__ head, int* __restrict__ nxt,
        float* __restrict__ out_zq, float* __restrict__ scal) {
    const int bx = blockIdx.x, by = blockIdx.y;
    const int n0 = bx * 64, c00 = by * 64;
    const int lane = threadIdx.x & 63, g = threadIdx.x >> 6;
    const int nt = bx >> 1, mb = (bx & 1) * 64;

    // phase 1: min over 128 j-rows for the block's 64 n; lane l ends with n0+l's key
    unsigned mn = 0xFFFFFFFFu;
    const unsigned* base = pdk + (((size_t)nt * 128 + g * 32) << 7) + mb + lane;
    #pragma unroll 8
    for (int jj = 0; jj < 32; ++jj) {
        unsigned key = base[jj << 7];          // coalesced 256B run per j
        mn = key < mn ? key : mn;
    }
    __shared__ unsigned part[4][64];
    part[g][lane] = mn;
    __syncthreads();
    unsigned k0v = part[0][lane], k1v = part[1][lane];
    unsigned k2v = part[2][lane], k3v = part[3][lane];
    unsigned f01 = k0v < k1v ? k0v : k1v;
    unsigned f23 = k2v < k3v ? k2v : k3v;
    unsigned fkey = f01 < f23 ? f01 : f23;
    int idxn = (int)(fkey & 8191u);
    int n = n0 + lane;

    if (by == 0) {
        if (g == 0) {
            out_idx[n] = (float)idxn;
            atomicAdd(cnt + idxn, 1);
            int old = atomicExch(head + idxn, n + 1);   // 0 = end-of-list
            nxt[n] = old;
        } else if (g == 1) {
            float cv = cs[n];
            #pragma unroll
            for (int m = 1; m < 64; m <<= 1) cv += __shfl_xor(cv, m, 64);
            if (lane == 0) atomicAdd(scal + 1, cv);
        }
    }

    // phase 2: z_q gather + straight-through write + loss
    int b = n >> 10, hw = n & 1023;
    const float* zr = z + (size_t)b * CHW + hw;
    const float* er = emb + (size_t)idxn * 256;
    float* oz = out_zq + (size_t)b * CHW + hw;
    float ls = 0.f;
    #pragma unroll
    for (int q = 0; q < 4; ++q) {
        int c = c00 + g * 16 + q * 4;
        float4 e4 = *(const float4*)(er + c);
        float ev[4] = {e4.x, e4.y, e4.z, e4.w};
        #pragma unroll
        for (int r = 0; r < 4; ++r) {
            float zp = zr[(size_t)(c + r) << 10];
            float dif = ev[r] - zp;
            oz[(size_t)(c + r) << 10] = zp + dif;
            ls = fmaf(dif, dif, ls);
        }
    }
    #pragma unroll
    for (int m = 1; m < 64; m <<= 1) ls += __shfl_xor(ls, m, 64);
    __shared__ float red[4];
    if (lane == 0) red[g] = ls;
    __syncthreads();
    if (threadIdx.x == 0) atomicAdd(scal, red[0] + red[1] + red[2] + red[3]);
}

// ---- finalize: list-walk dw (zf reconstructed from Ah/Am), new_cs, ema, embedding, loss ----
__global__ __launch_bounds__(256) void k_fin(const float* __restrict__ cs, const float* __restrict__ ema,
        const int* __restrict__ head, const int* __restrict__ nxt,
        const _Float16* __restrict__ Ah, const _Float16* __restrict__ Am,
        const float* __restrict__ scal, const int* __restrict__ cnt,
        float* __restrict__ out_ncs, float* __restrict__ out_ema,
        float* __restrict__ out_emb, float* __restrict__ out_loss) {
    int k = blockIdx.x * 4 + (threadIdx.x >> 6);
    int lane = threadIdx.x & 63;
    // dw[k][:] = sum over assigned n of zf[n][:], zf ~= h + m' (m' unscaled residual)
    float4 dwv = {0.f, 0.f, 0.f, 0.f};
    int cur = head[k];
    while (cur) {
        int n = cur - 1;
        v4h hh = *(const v4h*)(Ah + (size_t)n * 256 + lane * 4);
        v4h mm = *(const v4h*)(Am + (size_t)n * 256 + lane * 4);
        dwv.x += (float)hh[0] + (float)mm[0];
        dwv.y += (float)hh[1] + (float)mm[1];
        dwv.z += (float)hh[2] + (float)mm[2];
        dwv.w += (float)hh[3] + (float)mm[3];
        cur = nxt[n];
    }
    const float C1 = (float)(1.0 - 0.99);
    const float KEPS = (float)(8192 * 1e-5);
    float ncs0v = cs[k] * 0.99f + C1 * (float)cnt[k];
    float nsum = 0.99f * scal[1] + C1 * 8192.0f;   // sum(counts) == N == 8192
    float ncs = (ncs0v + 1e-5f) / (nsum + KEPS) * nsum;
    if (lane == 0) out_ncs[k] = ncs;
    size_t base = (size_t)k * 256 + lane * 4;
    float4 e4 = *(const float4*)(ema + base);
    float r0 = e4.x * 0.99f + C1 * dwv.x;
    float r1 = e4.y * 0.99f + C1 * dwv.y;
    float r2 = e4.z * 0.99f + C1 * dwv.z;
    float r3 = e4.w * 0.99f + C1 * dwv.w;
    out_ema[base + 0] = r0; out_ema[base + 1] = r1; out_ema[base + 2] = r2; out_ema[base + 3] = r3;
    out_emb[base + 0] = r0 / ncs; out_emb[base + 1] = r1 / ncs;
    out_emb[base + 2] = r2 / ncs; out_emb[base + 3] = r3 / ncs;
    if (blockIdx.x == 0 && threadIdx.x == 0) {
        float m = scal[0] * (1.0f / 2097152.0f);
        out_loss[0] = m + 0.25f * m;
    }
}

extern "C" void kernel_launch(void* const* d_in, const int* in_sizes, int n_in,
                              void* d_out, int out_size, void* d_ws, size_t ws_size,
                              hipStream_t stream) {
    const float* z   = (const float*)d_in[0];
    const float* emb = (const float*)d_in[1];
    const float* cs  = (const float*)d_in[2];
    const float* ema = (const float*)d_in[3];
    float* out = (float*)d_out;
    float* wsf = (float*)d_ws;

    float* asq  = wsf + OFF_ASQ;
    float* bsq  = wsf + OFF_BSQ;
    int*   cnt  = (int*)(wsf + OFF_CNT);
    int*   head = (int*)(wsf + OFF_HEAD);
    int*   nxt  = (int*)(wsf + OFF_NXT);
    float* scal = wsf + OFF_SCAL;
    _Float16* Ah = (_Float16*)(wsf + OFF_AH);
    _Float16* Am = (_Float16*)(wsf + OFF_AM);
    _Float16* Bh = (_Float16*)(wsf + OFF_BH);
    _Float16* Bm = (_Float16*)(wsf + OFF_BM);

    float* out_zq   = out;                 // [2097152]
    float* out_loss = out + 2097152;       // [1]
    float* out_idx  = out + 2097153;       // [8192]
    float* out_ncs  = out + 2105345;       // [8192]
    float* out_ema  = out + 2113537;       // [2097152]
    float* out_emb  = out + 4210689;       // [2097152]

    // pdk (4 MB) aliases the dead out_ema region: written by k_main, read by k_zqr,
    // overwritten only later by k_fin's out_ema stores.
    unsigned* pdk = (unsigned*)(out + 2113540);   // 16B-aligned

    k_prep<<<2608, 256, 0, stream>>>(z, emb, asq, bsq, Bh, Bm, Ah, Am, wsf + OFF_CNT);
    k_main<<<1024, 512, 0, stream>>>(Ah, Am, Bh, Bm, asq, bsq, pdk);
    k_zqr<<<dim3(128, 4), 256, 0, stream>>>(pdk, z, emb, cs, out_idx, cnt, head, nxt, out_zq, scal);
    k_fin<<<2048, 256, 0, stream>>>(cs, ema, head, nxt, Ah, Am, scal, cnt, out_ncs, out_ema, out_emb, out_loss);
}

// Round 6
// 222.890 us; speedup vs baseline: 1.6692x; 1.0345x over previous
//
#include <hip/hip_runtime.h>

#define CHW 262144   // C*H*W = 256*32*32
#define HWD 1024     // H*W

typedef _Float16 v8h __attribute__((ext_vector_type(8)));
typedef _Float16 v4h __attribute__((ext_vector_type(4)));
typedef float    v4f __attribute__((ext_vector_type(4)));

// ws layout (float offsets), total 4235272 floats = 16.9 MB
static const unsigned OFF_ASQ  = 0;        // ||z_n||^2 [8192]
static const unsigned OFF_BSQ  = 8192;     // ||e_k||^2 [8192]
static const unsigned OFF_CNT  = 16384;    // counts (int, zeroed by k_prep) [8192]
static const unsigned OFF_HEAD = 24576;    // list heads, n+1, 0=end (int, zeroed) [8192]
static const unsigned OFF_NXT  = 32768;    // list next (int; fully written) [8192]
static const unsigned OFF_SCAL = 40960;    // [0]=loss_sum [1]=sum(cs) (zeroed) [8]
static const unsigned OFF_AH   = 40968;    // Ah fp16 [8192*256] (1048576 floats, 16B-aligned)
static const unsigned OFF_AM   = 1089544;  // Am fp16 (UNSCALED residuals since r5)
static const unsigned OFF_BH   = 2138120;  // Bh fp16
static const unsigned OFF_BM   = 3186696;  // Bm fp16 (UNSCALED residuals since r5)
// pdk u32[8192][128] (4 MB) lives in d_out's out_ema region (dead until k_fin writes it)

#define GLL(g, l) __builtin_amdgcn_global_load_lds( \
    (const __attribute__((address_space(1))) void*)(g), \
    (__attribute__((address_space(3))) void*)(l), 16, 0, 0)

// ---- stage 1: ||z||^2 | emb->bsq+fp16 split | z transpose+split | zero cnt/head/scal ----
// r5: residual matrices Am/Bm are stored UNSCALED (m' = fl16(x - h)); k_main folds all
// three products into one accumulator (S = acc * 2^-13). Sub-normal residuals contribute
// <1e-7 to z.e (vs 7.6e-6 key bucket) — harmless even if MFMA flushes denormals.
__global__ __launch_bounds__(256) void k_prep(const float* __restrict__ z,
        const float* __restrict__ emb, float* __restrict__ asq, float* __restrict__ bsq,
        _Float16* __restrict__ Bh, _Float16* __restrict__ Bm,
        _Float16* __restrict__ Ah, _Float16* __restrict__ Am,
        float* __restrict__ zerobase) {
    int bx = blockIdx.x;
    int t = threadIdx.x;
    if (bx < 32) {
        // ||z_n||^2 — EXACT sequential 256-chain (bits feed the argmin; do not reorder)
        int n = bx * 256 + t;
        const float* p = z + (size_t)(n >> 10) * CHW + (n & 1023);
        float s = 0.f;
        #pragma unroll 8
        for (int c = 0; c < 256; ++c) { float v = p[(size_t)c << 10]; s = fmaf(v, v, s); }
        asq[n] = s;
    } else if (bx < 2080) {
        int w = (bx - 32) * 4 + (t >> 6);
        int lane = t & 63;
        float4 v = *(const float4*)(emb + (size_t)w * 256 + lane * 4);
        float s = v.x * v.x;
        s = fmaf(v.y, v.y, s); s = fmaf(v.z, v.z, s); s = fmaf(v.w, v.w, s);
        #pragma unroll
        for (int m = 1; m < 64; m <<= 1) s += __shfl_xor(s, m, 64);
        if (lane == 0) bsq[w] = s;
        float e0 = v.x * 8192.0f, e1 = v.y * 8192.0f, e2 = v.z * 8192.0f, e3 = v.w * 8192.0f;
        _Float16 h0 = (_Float16)e0, h1 = (_Float16)e1, h2 = (_Float16)e2, h3 = (_Float16)e3;
        v4h hv = {h0, h1, h2, h3};
        v4h mv = {(_Float16)(e0 - (float)h0),
                  (_Float16)(e1 - (float)h1),
                  (_Float16)(e2 - (float)h2),
                  (_Float16)(e3 - (float)h3)};
        *(v4h*)(Bh + (size_t)w * 256 + lane * 4) = hv;
        *(v4h*)(Bm + (size_t)w * 256 + lane * 4) = mv;
    } else if (bx < 2592) {
        __shared__ float s[64][65];
        int blk = bx - 2080;
        int hw0 = (blk & 15) * 64;
        int c0  = ((blk >> 4) & 3) * 64;
        int b   = blk >> 6;
        #pragma unroll
        for (int ii = 0; ii < 16; ++ii) {
            int e = t + ii * 256;
            int c = e >> 6, x = e & 63;
            s[c][x] = z[(size_t)b * CHW + (size_t)(c0 + c) * HWD + hw0 + x];
        }
        __syncthreads();
        int n = t & 63, cseg = (t >> 6) * 16;
        _Float16 hbuf[16], mbuf[16];
        #pragma unroll
        for (int j = 0; j < 16; ++j) {
            float v = s[cseg + j][n];
            _Float16 h = (_Float16)v;
            float r = v - (float)h;
            hbuf[j] = h;
            mbuf[j] = (_Float16)r;
        }
        size_t off = ((size_t)b * 1024 + hw0 + n) * 256 + c0 + cseg;
        *(v8h*)(Ah + off)     = *(v8h*)(hbuf);
        *(v8h*)(Ah + off + 8) = *(v8h*)(hbuf + 8);
        *(v8h*)(Am + off)     = *(v8h*)(mbuf);
        *(v8h*)(Am + off + 8) = *(v8h*)(mbuf + 8);
    } else {
        // zero cnt[8192] + head[8192] + scal
        int idx = (bx - 2592) * 1024 + t * 4;   // 16 blocks cover 16384 u32
        *(float4*)(zerobase + idx) = (float4){0.f, 0.f, 0.f, 0.f};
        if (bx == 2592 && t == 0)
            *(float4*)(zerobase + 24576) = (float4){0.f, 0.f, 0.f, 0.f};   // scal[0..3]
    }
}

// ---- main: 256x256 tile, 512 threads (8 waves of 64x128), j-granular pipeline ----
// r6: break the barrier-forced phase storm. r5 grouped reads into two bursts (fenced by
// setprio/sched_barrier) -> all 8 waves stormed the LDS pipe together while MFMA idled
// (step ~9225cyc vs MFMA busy 3725). Now each step is: read fa/fam (8 b128), then 8
// unrolled j-chunks of {prefetch fb[j+1]/fbm[j+1] (2 b128) ; 12 MFMAs col j} with two
// alternating named register pairs. LDS reads run ~10% duty UNDER the MFMA stream; no
// scheduler fences inside the step. Target step ~4300cyc.
// FROZEN numerics (= r5, passed): per-acc chain h*h, h*m', m'*h per step, steps 0..7;
// single accumulator; S = acc * 2^-13; epilogue bits unchanged.
__global__ __launch_bounds__(512, 2) void k_main(
        const _Float16* __restrict__ Ah, const _Float16* __restrict__ Am,
        const _Float16* __restrict__ Bh, const _Float16* __restrict__ Bm,
        const float* __restrict__ asq, const float* __restrict__ bsq,
        unsigned* __restrict__ pdk) {
    __shared__ _Float16 lds[65536];  // 128 KB: 2 bufs x 64 KB (AH 16K|AM 16K|BH 16K|BM 16K)
    // XCD-pinned swizzle (round-robin bid->XCD): xcd owns kt in [xcd*4, xcd*4+4)
    // (B slice 1 MB -> L2-resident); within XCD, kt-local sweeps fastest (A reuse x4).
    const int bid = blockIdx.x;
    const int xcd = bid & 7, sblk = bid >> 3;  // sblk in [0,128)
    const int kt = xcd * 4 + (sblk & 3);       // [0,32)
    const int nt = sblk >> 2;                  // [0,32)
    const int n0 = nt * 256, k0 = kt * 256;
    const int t = threadIdx.x;
    const int lane = t & 63, w = t >> 6;       // w in [0,8)
    const int wrow = w >> 1, wcol = w & 1;     // 4x2 wave grid, each wave 64 rows x 128 cols
    const int lm = lane & 15, quad = lane >> 4;

    v4f acc[4][8];
    #pragma unroll
    for (int i = 0; i < 4; ++i)
        #pragma unroll
        for (int j = 0; j < 8; ++j) acc[i][j] = (v4f){0.f,0.f,0.f,0.f};

    // staging: thread t covers row-chunks t and t+512 per matrix (rows 0-127 / 128-255);
    // chunk swizzle c4 = (t&3) ^ ((row>>1)&3) is row-periodic mod 4 (128%4==0 -> same c40).
    const int row0 = t >> 2;                   // [0,128)
    const int c40 = (t & 3) ^ ((row0 >> 1) & 3);
    const char* gA  = (const char*)Ah + (size_t)(n0 + row0) * 512 + c40 * 16;
    const char* gAm = (const char*)Am + (size_t)(n0 + row0) * 512 + c40 * 16;
    const char* gB  = (const char*)Bh + (size_t)(k0 + row0) * 512 + c40 * 16;
    const char* gBm = (const char*)Bm + (size_t)(k0 + row0) * 512 + c40 * 16;

    // per-buf layout (halves): AH [0,8192) | AM [8192,16384) | BH [16384,24576) | BM [24576,32768)
    int sa[4], sb[8];
    #pragma unroll
    for (int i = 0; i < 4; ++i) {
        int mr = wrow * 64 + i * 16 + lm;      // [0,256)
        sa[i] = mr * 32 + ((quad ^ ((mr >> 1) & 3)) * 8);
    }
    #pragma unroll
    for (int j = 0; j < 8; ++j) {
        int nr = wcol * 128 + j * 16 + lm;     // [0,256)
        sb[j] = nr * 32 + ((quad ^ ((nr >> 1) & 3)) * 8);
    }

    auto stage = [&](int s, int buf) {         // 8 GLL = 64 KB per (block, K32-step)
        const size_t co = (size_t)s * 64;      // 32 halves per step
        _Float16* l = lds + buf * 32768 + t * 8;
        GLL(gA + co,           l);             // Ah rows 0-127
        GLL(gA + co + 65536,   l + 4096);      // Ah rows 128-255
        GLL(gAm + co,          l + 8192);
        GLL(gAm + co + 65536,  l + 12288);
        GLL(gB + co,           l + 16384);
        GLL(gB + co + 65536,   l + 20480);
        GLL(gBm + co,          l + 24576);
        GLL(gBm + co + 65536,  l + 28672);
    };

#define MFMA16(A, B, C) __builtin_amdgcn_mfma_f32_16x16x32_f16(A, B, C, 0, 0, 0)
    // per-element chain order is FROZEN: h*h, h*m', m'*h into ONE acc
#define LOADB(FB, FBM, J) do { \
        FB  = *(const v8h*)(L + 16384 + sb[J]); \
        FBM = *(const v8h*)(L + 24576 + sb[J]); \
    } while (0)
#define MCOL(J, FB, FBM) do { \
        acc[0][J] = MFMA16(fa0,  FB,  acc[0][J]); \
        acc[0][J] = MFMA16(fa0,  FBM, acc[0][J]); \
        acc[0][J] = MFMA16(fam0, FB,  acc[0][J]); \
        acc[1][J] = MFMA16(fa1,  FB,  acc[1][J]); \
        acc[1][J] = MFMA16(fa1,  FBM, acc[1][J]); \
        acc[1][J] = MFMA16(fam1, FB,  acc[1][J]); \
        acc[2][J] = MFMA16(fa2,  FB,  acc[2][J]); \
        acc[2][J] = MFMA16(fa2,  FBM, acc[2][J]); \
        acc[2][J] = MFMA16(fam2, FB,  acc[2][J]); \
        acc[3][J] = MFMA16(fa3,  FB,  acc[3][J]); \
        acc[3][J] = MFMA16(fa3,  FBM, acc[3][J]); \
        acc[3][J] = MFMA16(fam3, FB,  acc[3][J]); \
    } while (0)

    stage(0, 0);
    for (int s = 0; s < 8; ++s) {
        // own stage(s) retired (issued a full step ago -> wait is ~free), then rendezvous:
        // after the barrier ALL waves' stage(s) writes have landed; buf (s+1)&1 is reusable.
        asm volatile("s_waitcnt vmcnt(0)" ::: "memory");
        __builtin_amdgcn_s_barrier();
        __builtin_amdgcn_sched_barrier(0);     // nothing hoists above the wait+barrier
        if (s < 7) stage(s + 1, (s + 1) & 1);
        const _Float16* L = lds + (s & 1) * 32768;

        // A fragments once per step
        v8h fa0  = *(const v8h*)(L + sa[0]);
        v8h fa1  = *(const v8h*)(L + sa[1]);
        v8h fa2  = *(const v8h*)(L + sa[2]);
        v8h fa3  = *(const v8h*)(L + sa[3]);
        v8h fam0 = *(const v8h*)(L + 8192 + sa[0]);
        v8h fam1 = *(const v8h*)(L + 8192 + sa[1]);
        v8h fam2 = *(const v8h*)(L + 8192 + sa[2]);
        v8h fam3 = *(const v8h*)(L + 8192 + sa[3]);

        // j-granular pipeline: prefetch column j+1 while computing column j (no fences;
        // compiler emits fine lgkmcnt; each 2-read prefetch hides under 12 MFMAs)
        v8h fbA, fbmA, fbB, fbmB;
        LOADB(fbA, fbmA, 0);
        LOADB(fbB, fbmB, 1);  MCOL(0, fbA, fbmA);
        LOADB(fbA, fbmA, 2);  MCOL(1, fbB, fbmB);
        LOADB(fbB, fbmB, 3);  MCOL(2, fbA, fbmA);
        LOADB(fbA, fbmA, 4);  MCOL(3, fbB, fbmB);
        LOADB(fbB, fbmB, 5);  MCOL(4, fbA, fbmA);
        LOADB(fbA, fbmA, 6);  MCOL(5, fbB, fbmB);
        LOADB(fbB, fbmB, 7);  MCOL(6, fbA, fbmA);
        MCOL(7, fbB, fbmB);
    }
#undef MCOL
#undef LOADB
#undef MFMA16

    // epilogue: S = acc * 2^-13; d = fl(fl(a+b) - 2*S); key = ((d-a)*2^16+32768)<<13 | k
    float bvv[8];
    #pragma unroll
    for (int j = 0; j < 8; ++j) bvv[j] = bsq[k0 + wcol * 128 + j * 16 + lm];
    __syncthreads();                            // LDS reuse for key assembly
    unsigned* lrow = (unsigned*)lds;            // [1024]: (mm>>7)*512 + kh*128 + (mm&127)
    #pragma unroll
    for (int i = 0; i < 4; ++i) {
        #pragma unroll
        for (int r = 0; r < 4; ++r) {
            int mm = wrow * 64 + i * 16 + quad * 4 + r;     // [0,256)
            float av_ = asq[n0 + mm];
            #pragma unroll
            for (int jh = 0; jh < 2; ++jh) {
                unsigned best = 0xFFFFFFFFu;
                #pragma unroll
                for (int j4 = 0; j4 < 4; ++j4) {
                    const int j = jh * 4 + j4;
                    float S = acc[i][j][r] * 1.220703125e-4f;   // * 2^-13
                    float dd = (av_ + bvv[j]) - 2.0f * S;
                    float gv = dd - av_;                        // exact (Sterbenz)
                    int mi = (int)(gv * 65536.0f) + 32768;      // exact integer
                    int col = k0 + wcol * 128 + j * 16 + lm;
                    unsigned key = ((unsigned)mi << 13) | (unsigned)col;
                    best = key < best ? key : best;
                }
                #pragma unroll
                for (int xm = 1; xm < 16; xm <<= 1) {           // reduce over lm per quad
                    unsigned o = __shfl_xor(best, xm, 64);
                    best = o < best ? o : best;
                }
                if (lm == 0)
                    lrow[(mm >> 7) * 512 + (wcol * 2 + jh) * 128 + (mm & 127)] = best;
            }
        }
    }
    __syncthreads();
    // dense coalesced store: pdk[(nt2)*128 + kt*4 + kh][n&127]; 1024 entries, 2/thread
    #pragma unroll
    for (int u = 0; u < 2; ++u) {
        int e = t + u * 512;
        pdk[((size_t)(nt * 2 + (e >> 9)) * 128 + kt * 4 + ((e >> 7) & 3)) * 128 + (e & 127)]
            = lrow[e];
    }
}

// ---- fused: per-block key reduce -> idx | lists/histogram/cs-sum (y==0) | z_q + loss ----
__global__ __launch_bounds__(256) void k_zqr(const unsigned* __restrict__ pdk,
        const float* __restrict__ z, const float* __restrict__ emb, const float* __restrict__ cs,
        float* __restrict__ out_idx, int* __restrict__ cnt,
        int* __restrict__ head, int* __restrict__ nxt,
        float* __restrict__ out_zq, float* __restrict__ scal) {
    const int bx = blockIdx.x, by = blockIdx.y;
    const int n0 = bx * 64, c00 = by * 64;
    const int lane = threadIdx.x & 63, g = threadIdx.x >> 6;
    const int nt = bx >> 1, mb = (bx & 1) * 64;

    // phase 1: min over 128 j-rows for the block's 64 n; lane l ends with n0+l's key
    unsigned mn = 0xFFFFFFFFu;
    const unsigned* base = pdk + (((size_t)nt * 128 + g * 32) << 7) + mb + lane;
    #pragma unroll 8
    for (int jj = 0; jj < 32; ++jj) {
        unsigned key = base[jj << 7];          // coalesced 256B run per j
        mn = key < mn ? key : mn;
    }
    __shared__ unsigned part[4][64];
    part[g][lane] = mn;
    __syncthreads();
    unsigned k0v = part[0][lane], k1v = part[1][lane];
    unsigned k2v = part[2][lane], k3v = part[3][lane];
    unsigned f01 = k0v < k1v ? k0v : k1v;
    unsigned f23 = k2v < k3v ? k2v : k3v;
    unsigned fkey = f01 < f23 ? f01 : f23;
    int idxn = (int)(fkey & 8191u);
    int n = n0 + lane;

    if (by == 0) {
        if (g == 0) {
            out_idx[n] = (float)idxn;
            atomicAdd(cnt + idxn, 1);
            int old = atomicExch(head + idxn, n + 1);   // 0 = end-of-list
            nxt[n] = old;
        } else if (g == 1) {
            float cv = cs[n];
            #pragma unroll
            for (int m = 1; m < 64; m <<= 1) cv += __shfl_xor(cv, m, 64);
            if (lane == 0) atomicAdd(scal + 1, cv);
        }
    }

    // phase 2: z_q gather + straight-through write + loss
    int b = n >> 10, hw = n & 1023;
    const float* zr = z + (size_t)b * CHW + hw;
    const float* er = emb + (size_t)idxn * 256;
    float* oz = out_zq + (size_t)b * CHW + hw;
    float ls = 0.f;
    #pragma unroll
    for (int q = 0; q < 4; ++q) {
        int c = c00 + g * 16 + q * 4;
        float4 e4 = *(const float4*)(er + c);
        float ev[4] = {e4.x, e4.y, e4.z, e4.w};
        #pragma unroll
        for (int r = 0; r < 4; ++r) {
            float zp = zr[(size_t)(c + r) << 10];
            float dif = ev[r] - zp;
            oz[(size_t)(c + r) << 10] = zp + dif;
            ls = fmaf(dif, dif, ls);
        }
    }
    #pragma unroll
    for (int m = 1; m < 64; m <<= 1) ls += __shfl_xor(ls, m, 64);
    __shared__ float red[4];
    if (lane == 0) red[g] = ls;
    __syncthreads();
    if (threadIdx.x == 0) atomicAdd(scal, red[0] + red[1] + red[2] + red[3]);
}

// ---- finalize: list-walk dw (zf reconstructed from Ah/Am), new_cs, ema, embedding, loss ----
__global__ __launch_bounds__(256) void k_fin(const float* __restrict__ cs, const float* __restrict__ ema,
        const int* __restrict__ head, const int* __restrict__ nxt,
        const _Float16* __restrict__ Ah, const _Float16* __restrict__ Am,
        const float* __restrict__ scal, const int* __restrict__ cnt,
        float* __restrict__ out_ncs, float* __restrict__ out_ema,
        float* __restrict__ out_emb, float* __restrict__ out_loss) {
    int k = blockIdx.x * 4 + (threadIdx.x >> 6);
    int lane = threadIdx.x & 63;
    // dw[k][:] = sum over assigned n of zf[n][:], zf ~= h + m' (m' unscaled residual)
    float4 dwv = {0.f, 0.f, 0.f, 0.f};
    int cur = head[k];
    while (cur) {
        int n = cur - 1;
        v4h hh = *(const v4h*)(Ah + (size_t)n * 256 + lane * 4);
        v4h mm = *(const v4h*)(Am + (size_t)n * 256 + lane * 4);
        dwv.x += (float)hh[0] + (float)mm[0];
        dwv.y += (float)hh[1] + (float)mm[1];
        dwv.z += (float)hh[2] + (float)mm[2];
        dwv.w += (float)hh[3] + (float)mm[3];
        cur = nxt[n];
    }
    const float C1 = (float)(1.0 - 0.99);
    const float KEPS = (float)(8192 * 1e-5);
    float ncs0v = cs[k] * 0.99f + C1 * (float)cnt[k];
    float nsum = 0.99f * scal[1] + C1 * 8192.0f;   // sum(counts) == N == 8192
    float ncs = (ncs0v + 1e-5f) / (nsum + KEPS) * nsum;
    if (lane == 0) out_ncs[k] = ncs;
    size_t base = (size_t)k * 256 + lane * 4;
    float4 e4 = *(const float4*)(ema + base);
    float r0 = e4.x * 0.99f + C1 * dwv.x;
    float r1 = e4.y * 0.99f + C1 * dwv.y;
    float r2 = e4.z * 0.99f + C1 * dwv.z;
    float r3 = e4.w * 0.99f + C1 * dwv.w;
    out_ema[base + 0] = r0; out_ema[base + 1] = r1; out_ema[base + 2] = r2; out_ema[base + 3] = r3;
    out_emb[base + 0] = r0 / ncs; out_emb[base + 1] = r1 / ncs;
    out_emb[base + 2] = r2 / ncs; out_emb[base + 3] = r3 / ncs;
    if (blockIdx.x == 0 && threadIdx.x == 0) {
        float m = scal[0] * (1.0f / 2097152.0f);
        out_loss[0] = m + 0.25f * m;
    }
}

extern "C" void kernel_launch(void* const* d_in, const int* in_sizes, int n_in,
                              void* d_out, int out_size, void* d_ws, size_t ws_size,
                              hipStream_t stream) {
    const float* z   = (const float*)d_in[0];
    const float* emb = (const float*)d_in[1];
    const float* cs  = (const float*)d_in[2];
    const float* ema = (const float*)d_in[3];
    float* out = (float*)d_out;
    float* wsf = (float*)d_ws;

    float* asq  = wsf + OFF_ASQ;
    float* bsq  = wsf + OFF_BSQ;
    int*   cnt  = (int*)(wsf + OFF_CNT);
    int*   head = (int*)(wsf + OFF_HEAD);
    int*   nxt  = (int*)(wsf + OFF_NXT);
    float* scal = wsf + OFF_SCAL;
    _Float16* Ah = (_Float16*)(wsf + OFF_AH);
    _Float16* Am = (_Float16*)(wsf + OFF_AM);
    _Float16* Bh = (_Float16*)(wsf + OFF_BH);
    _Float16* Bm = (_Float16*)(wsf + OFF_BM);

    float* out_zq   = out;                 // [2097152]
    float* out_loss = out + 2097152;       // [1]
    float* out_idx  = out + 2097153;       // [8192]
    float* out_ncs  = out + 2105345;       // [8192]
    float* out_ema  = out + 2113537;       // [2097152]
    float* out_emb  = out + 4210689;       // [2097152]

    // pdk (4 MB) aliases the dead out_ema region: written by k_main, read by k_zqr,
    // overwritten only later by k_fin's out_ema stores.
    unsigned* pdk = (unsigned*)(out + 2113540);   // 16B-aligned

    k_prep<<<2608, 256, 0, stream>>>(z, emb, asq, bsq, Bh, Bm, Ah, Am, wsf + OFF_CNT);
    k_main<<<1024, 512, 0, stream>>>(Ah, Am, Bh, Bm, asq, bsq, pdk);
    k_zqr<<<dim3(128, 4), 256, 0, stream>>>(pdk, z, emb, cs, out_idx, cnt, head, nxt, out_zq, scal);
    k_fin<<<2048, 256, 0, stream>>>(cs, ema, head, nxt, Ah, Am, scal, cnt, out_ncs, out_ema, out_emb, out_loss);
}